// Round 15
// baseline (591.041 us; speedup 1.0000x reference)
//
#include <hip/hip_runtime.h>
#include <hip/hip_bf16.h>
#include <stdint.h>

#define DIMC 512
#define NTOK 98
// M_TOTAL = 1024*98 = 100352 = 784 * 128

typedef float f32x4 __attribute__((ext_vector_type(4)));
typedef short bf16x8 __attribute__((ext_vector_type(8)));
typedef short bf16x4 __attribute__((ext_vector_type(4)));

__device__ inline unsigned short f2bf(float f) {
    union { float f; uint32_t u; } v; v.f = f;
    uint32_t r = v.u + 0x7fffu + ((v.u >> 16) & 1u);
    return (unsigned short)(r >> 16);
}

__device__ inline bf16x8 cvt8(float4 a, float4 b) {
    bf16x8 r;
    r[0] = (short)f2bf(a.x); r[1] = (short)f2bf(a.y);
    r[2] = (short)f2bf(a.z); r[3] = (short)f2bf(a.w);
    r[4] = (short)f2bf(b.x); r[5] = (short)f2bf(b.y);
    r[6] = (short)f2bf(b.z); r[7] = (short)f2bf(b.w);
    return r;
}

__device__ __forceinline__ void gload16(const void* g, void* l) {
    __builtin_amdgcn_global_load_lds(
        (const __attribute__((address_space(1))) unsigned int*)g,
        (__attribute__((address_space(3))) unsigned int*)l, 16, 0, 0);
}

#define CFENCE() __asm__ __volatile__("" ::: "memory")
#define BARRIER() do { CFENCE(); __builtin_amdgcn_s_barrier(); CFENCE(); } while (0)

// ---------------- fused fp32 -> bf16 convert for x, qkv_w, proj_w --------------
__global__ void k_cvt3(const float* __restrict__ s0, unsigned short* __restrict__ d0,
                       const float* __restrict__ s1, unsigned short* __restrict__ d1,
                       const float* __restrict__ s2, unsigned short* __restrict__ d2) {
    int b = blockIdx.x;
    const float* src; unsigned short* dst; int i;
    if (b < 25088)      { src = s0; dst = d0; i = b * 256 + threadIdx.x; }
    else if (b < 25472) { src = s1; dst = d1; i = (b - 25088) * 256 + threadIdx.x; }
    else                { src = s2; dst = d2; i = (b - 25472) * 256 + threadIdx.x; }
    float4 a = *(const float4*)(src + (size_t)i * 8);
    float4 c = *(const float4*)(src + (size_t)i * 8 + 4);
    *(bf16x8*)(dst + (size_t)i * 8) = cvt8(a, c);
}

// -------- combined bias+mask, TRANSPOSED for swapped QK^T: [slice][i:112][c:112]
__global__ void k_bm2(const float* __restrict__ table, const int* __restrict__ idx,
                      const float* __restrict__ mask, float* __restrict__ bm_t) {
    int slice = blockIdx.x;            // 0..1023 = b64*16 + h
    int b64 = slice >> 4, h = slice & 15;
    float* dst = bm_t + (size_t)slice * 12544;   // 112*112
    const float* mp = mask + (size_t)b64 * 9604;
    for (int t = threadIdx.x; t < 12544; t += blockDim.x) {
        int i = t / 112, c = t - i * 112;
        float v = -1e9f;
        if (c < NTOK && i < NTOK)
            v = (table[idx[i * NTOK + c] * 16 + h] + mp[i * NTOK + c])
                * 1.4426950408889634f;
        dst[t] = v;
    }
}

// ===== qkv GEMM: 128^2 tile, BK=64, 4 waves, 64KB LDS -> 2 blocks/CU ===========
// Counted-vmcnt 2-phase: stage tile t+1 (8 gloads), vmcnt(8) retires tile t,
// barrier, compute (32 MFMA/wave), barrier. Inter-block overlap hides barriers.
__global__ __launch_bounds__(256, 2)
void k_qkv4(const unsigned short* __restrict__ xb, const unsigned short* __restrict__ wb,
            const float* __restrict__ qb, unsigned short* __restrict__ qkvbuf) {
    __shared__ unsigned short As[2][128 * 64];   // [slot][row*64 + col]
    __shared__ unsigned short Bs[2][128 * 64];
    const int tid = threadIdx.x;
    const int wid = tid >> 6, l = tid & 63, g = l >> 4, li = l & 15;
    const int wm = wid >> 1, wn = wid & 1;
    const int id = blockIdx.x;                   // 9408 = 8 * 98 * 12
    const int xcd = id & 7, local = id >> 3;
    const int mt = xcd * 98 + local / 12;
    const int nt = local - (local / 12) * 12;
    const int m0 = mt * 128, n0 = nt * 128;

    // staging: chunk c = r*256+tid -> row = r*32 + (tid>>3), colgrp = tid&7
    // pre-swizzled source: logical colgrp = phys ^ (row&7); row&7 == srow&7
    const int srow = tid >> 3;
    const int scg  = tid & 7;
    const int sxor = (scg ^ (srow & 7)) * 8;     // elems
    const unsigned short* aGb = xb + (size_t)(m0 + srow) * DIMC + sxor;
    const unsigned short* bGb = wb + (size_t)(n0 + srow) * DIMC + sxor;
    const int lds_base = wid * 512;              // + r*2048 per chunk-set

    const int axor0 = ((0 + g) ^ (li & 7)) * 8;
    const int axor1 = ((4 + g) ^ (li & 7)) * 8;
    const int arow = (wm * 64 + li) * 64;
    const int brow = (wn * 64 + li) * 64;

    f32x4 acc[4][4] = {};

#define QSTAGE(s, ko) do {                                                   \
        _Pragma("unroll")                                                    \
        for (int r = 0; r < 4; ++r) {                                        \
            gload16(aGb + (size_t)(r * 32) * DIMC + (ko), &As[s][r * 2048 + lds_base]); \
            gload16(bGb + (size_t)(r * 32) * DIMC + (ko), &Bs[s][r * 2048 + lds_base]); \
        } } while (0)

    QSTAGE(0, 0);
    #pragma unroll
    for (int kt = 0; kt < 8; ++kt) {
        const int s = kt & 1;
        if (kt < 7) {
            QSTAGE(s ^ 1, (kt + 1) * 64);
            __asm__ __volatile__("s_waitcnt vmcnt(8)" ::: "memory");
        } else {
            __asm__ __volatile__("s_waitcnt vmcnt(0)" ::: "memory");
        }
        BARRIER();
        bf16x8 bfr[4][2];
        #pragma unroll
        for (int nq = 0; nq < 4; ++nq) {
            bfr[nq][0] = *(const bf16x8*)&Bs[s][brow + nq * 1024 + axor0];
            bfr[nq][1] = *(const bf16x8*)&Bs[s][brow + nq * 1024 + axor1];
        }
        #pragma unroll
        for (int mq = 0; mq < 4; ++mq) {
            bf16x8 a0 = *(const bf16x8*)&As[s][arow + mq * 1024 + axor0];
            bf16x8 a1 = *(const bf16x8*)&As[s][arow + mq * 1024 + axor1];
            __builtin_amdgcn_s_setprio(1);
            #pragma unroll
            for (int nq = 0; nq < 4; ++nq) {
                acc[mq][nq] = __builtin_amdgcn_mfma_f32_16x16x32_bf16(
                    bfr[nq][0], a0, acc[mq][nq], 0, 0, 0);
                acc[mq][nq] = __builtin_amdgcn_mfma_f32_16x16x32_bf16(
                    bfr[nq][1], a1, acc[mq][nq], 0, 0, 0);
            }
            __builtin_amdgcn_s_setprio(0);
        }
        BARRIER();
    }
#undef QSTAGE

    // epilogue: swapped layout -> thread's quad = row (m=li) x 4 consecutive cols
    #pragma unroll
    for (int mq = 0; mq < 4; ++mq) {
        int row = m0 + wm * 64 + mq * 16 + li;
        unsigned bw = (unsigned)row / 98u;
        unsigned nn_ = (unsigned)row - bw * 98u;
        unsigned short* rbase = qkvbuf + (size_t)bw * 150528u + nn_ * 32u;
        #pragma unroll
        for (int nq = 0; nq < 4; ++nq) {
            int col0 = n0 + wn * 64 + nq * 16 + g * 4;
            int which = col0 >> 9;
            int h = (col0 >> 5) & 15;
            int d0 = col0 & 31;
            float4 bv = *(const float4*)(qb + col0);
            float sc = (which == 0)
                ? (0.17677669529663689f * 1.4426950408889634f) : 1.0f;
            bf16x4 pk;
            pk[0] = (short)f2bf((acc[mq][nq][0] + bv.x) * sc);
            pk[1] = (short)f2bf((acc[mq][nq][1] + bv.y) * sc);
            pk[2] = (short)f2bf((acc[mq][nq][2] + bv.z) * sc);
            pk[3] = (short)f2bf((acc[mq][nq][3] + bv.w) * sc);
            *(bf16x4*)(rbase + (size_t)(h * 3 + which) * 3136u + d0) = pk;
        }
    }
}

// ===== proj GEMM: same 128^2 / 2-blocks-per-CU pipeline, A gathered ============
__global__ __launch_bounds__(256, 2)
void k_proj4(const unsigned short* __restrict__ qkvbuf,
             const unsigned short* __restrict__ wb,
             const float* __restrict__ pb, float* __restrict__ out) {
    __shared__ unsigned short As[2][128 * 64];
    __shared__ unsigned short Bs[2][128 * 64];
    const int tid = threadIdx.x;
    const int wid = tid >> 6, l = tid & 63, g = l >> 4, li = l & 15;
    const int wm = wid >> 1, wn = wid & 1;
    const int id = blockIdx.x;                   // 3136 = 8 * 98 * 4
    const int xcd = id & 7, local = id >> 3;
    const int mt = xcd * 98 + local / 4;
    const int nt = local & 3;
    const int m0 = mt * 128, n0 = nt * 128;

    const int srow = tid >> 3;
    const int scg  = tid & 7;
    const int cgx  = scg ^ (srow & 7);
    const unsigned short* aG[4];
    const unsigned short* bG[4];
    #pragma unroll
    for (int r = 0; r < 4; ++r) {
        int R = m0 + r * 32 + srow;
        unsigned bw = (unsigned)R / 98u, nn = (unsigned)R - bw * 98u;
        aG[r] = qkvbuf + (size_t)bw * 150528u + nn * 32u
                + (size_t)(cgx >> 2) * 9408u + (cgx & 3) * 8;
        bG[r] = wb + (size_t)(n0 + r * 32 + srow) * DIMC + cgx * 8;
    }
    const int lds_base = wid * 512;

    const int axor0 = ((0 + g) ^ (li & 7)) * 8;
    const int axor1 = ((4 + g) ^ (li & 7)) * 8;
    const int arow = (wm * 64 + li) * 64;
    const int brow = (wn * 64 + li) * 64;

    f32x4 acc[4][4] = {};

#define PSTAGE(s, kt) do {                                                   \
        _Pragma("unroll")                                                    \
        for (int r = 0; r < 4; ++r) {                                        \
            gload16(aG[r] + (size_t)(kt) * 18816u, &As[s][r * 2048 + lds_base]); \
            gload16(bG[r] + (kt) * 64, &Bs[s][r * 2048 + lds_base]);         \
        } } while (0)

    PSTAGE(0, 0);
    #pragma unroll
    for (int kt = 0; kt < 8; ++kt) {
        const int s = kt & 1;
        if (kt < 7) {
            PSTAGE(s ^ 1, kt + 1);
            __asm__ __volatile__("s_waitcnt vmcnt(8)" ::: "memory");
        } else {
            __asm__ __volatile__("s_waitcnt vmcnt(0)" ::: "memory");
        }
        BARRIER();
        bf16x8 bfr[4][2];
        #pragma unroll
        for (int nq = 0; nq < 4; ++nq) {
            bfr[nq][0] = *(const bf16x8*)&Bs[s][brow + nq * 1024 + axor0];
            bfr[nq][1] = *(const bf16x8*)&Bs[s][brow + nq * 1024 + axor1];
        }
        #pragma unroll
        for (int mq = 0; mq < 4; ++mq) {
            bf16x8 a0 = *(const bf16x8*)&As[s][arow + mq * 1024 + axor0];
            bf16x8 a1 = *(const bf16x8*)&As[s][arow + mq * 1024 + axor1];
            __builtin_amdgcn_s_setprio(1);
            #pragma unroll
            for (int nq = 0; nq < 4; ++nq) {
                acc[mq][nq] = __builtin_amdgcn_mfma_f32_16x16x32_bf16(
                    bfr[nq][0], a0, acc[mq][nq], 0, 0, 0);
                acc[mq][nq] = __builtin_amdgcn_mfma_f32_16x16x32_bf16(
                    bfr[nq][1], a1, acc[mq][nq], 0, 0, 0);
            }
            __builtin_amdgcn_s_setprio(0);
        }
        BARRIER();
    }
#undef PSTAGE

    #pragma unroll
    for (int mq = 0; mq < 4; ++mq) {
        int row2 = m0 + wm * 64 + mq * 16 + li;
        float* orow = out + (size_t)row2 * DIMC;
        #pragma unroll
        for (int nq = 0; nq < 4; ++nq) {
            int col0 = n0 + wn * 64 + nq * 16 + g * 4;
            float4 bv = *(const float4*)(pb + col0);
            float4 v;
            v.x = acc[mq][nq][0] + bv.x;
            v.y = acc[mq][nq][1] + bv.y;
            v.z = acc[mq][nq][2] + bv.z;
            v.w = acc[mq][nq][3] + bv.w;
            *(float4*)(orow + col0) = v;
        }
    }
}

// ------- attention: persistent, dbuf K/V, SWAPPED QK^T (S^T = K x Q) -----------
__global__ __launch_bounds__(448)
void k_attn4(unsigned short* __restrict__ qkvbuf, const float* __restrict__ bm_t) {
    __shared__ short Ks[2][112][36];
    __shared__ short Vt[2][32][132];
    __shared__ short Ps[7][16][132];   // [wave][q-row][k]; k 112..127 zeroed once

    const int tid = threadIdx.x;
    const int w = tid >> 6, l = tid & 63, g = l >> 4, li = l & 15;

    const int id = blockIdx.x;                 // 2048
    const int slice = id >> 1, mh = id & 1;    // slice = (b%64)*16 + h

    const float* bmp = bm_t + (size_t)slice * 12544 + (16 * w + li) * 112 + g * 4;
    f32x4 bmf[7];
    #pragma unroll
    for (int j = 0; j < 7; ++j)
        bmf[j] = *(const f32x4*)(bmp + 16 * j);

    #pragma unroll
    for (int bsel = 0; bsel < 2; ++bsel) {
        Ks[bsel][98 + (tid >> 5)][tid & 31] = 0;
        for (int t2 = tid; t2 < 32 * 34; t2 += 448) {
            int d = t2 / 34, c = t2 % 34;
            Vt[bsel][d][98 + c] = 0;
        }
    }
    {
        bf16x4 z = {};
        *(bf16x4*)&Ps[w][li][112 + g * 4] = z;
    }

    const int krow = tid >> 2, kseg = (tid & 3) * 8;
    const size_t step = (size_t)1024 * 9408;
    unsigned short* qslot = qkvbuf + (size_t)(mh * 8192 + slice) * 9408;

    bf16x8 kreg = {}, vreg = {}, aqc, aqn;
    if (tid < 392) {
        kreg = *(const bf16x8*)(qslot + 3136 + krow * 32 + kseg);
        vreg = *(const bf16x8*)(qslot + 6272 + krow * 32 + kseg);
    }
    aqc = *(const bf16x8*)(qslot + (16 * w + li) * 32 + g * 8);
    if (tid < 392) {
        *(bf16x8*)&Ks[0][krow][kseg] = kreg;
        #pragma unroll
        for (int j = 0; j < 8; ++j) Vt[0][kseg + j][krow] = vreg[j];
    }

    for (int it = 0; it < 8; ++it) {
        const int b = it & 1;
        __syncthreads();   // buf b staged visible

        unsigned short* qnext = qslot + step;
        if (it < 7) {
            if (tid < 392) {
                kreg = *(const bf16x8*)(qnext + 3136 + krow * 32 + kseg);
                vreg = *(const bf16x8*)(qnext + 6272 + krow * 32 + kseg);
            }
            aqn = *(const bf16x8*)(qnext + (16 * w + li) * 32 + g * 8);
        }

        // S^T = K @ Q^T + bias^T: lane holds S[q=li][k=16j+g*4+r]
        f32x4 s[7];
        __builtin_amdgcn_s_setprio(1);
        #pragma unroll
        for (int j = 0; j < 7; ++j) {
            bf16x8 bk = *(bf16x8*)&Ks[b][16 * j + li][g * 8];
            s[j] = __builtin_amdgcn_mfma_f32_16x16x32_bf16(bk, aqc, bmf[j], 0, 0, 0);
        }
        __builtin_amdgcn_s_setprio(0);

        float p[7][4];
        float sum = 0.f;
        #pragma unroll
        for (int j = 0; j < 7; ++j)
            #pragma unroll
            for (int r = 0; r < 4; ++r) {
                p[j][r] = exp2f(s[j][r]);
                sum += p[j][r];
            }
        sum += __shfl_xor(sum, 16);
        sum += __shfl_xor(sum, 32);
        float sinv = 1.0f / sum;

        #pragma unroll
        for (int j = 0; j < 7; ++j) {
            bf16x4 pk;
            pk[0] = (short)f2bf(p[j][0] * sinv);
            pk[1] = (short)f2bf(p[j][1] * sinv);
            pk[2] = (short)f2bf(p[j][2] * sinv);
            pk[3] = (short)f2bf(p[j][3] * sinv);
            *(bf16x4*)&Ps[w][li][16 * j + g * 4] = pk;
        }

        __asm__ __volatile__("s_waitcnt lgkmcnt(0)" ::: "memory");
        __builtin_amdgcn_sched_barrier(0);

        f32x4 o[2] = {};
        __builtin_amdgcn_s_setprio(1);
        #pragma unroll
        for (int ks = 0; ks < 4; ++ks) {
            bf16x8 pa = *(bf16x8*)&Ps[w][li][ks * 32 + g * 8];
            #pragma unroll
            for (int ct = 0; ct < 2; ++ct) {
                bf16x8 vb = *(bf16x8*)&Vt[b][ct * 16 + li][ks * 32 + g * 8];
                o[ct] = __builtin_amdgcn_mfma_f32_16x16x32_bf16(pa, vb, o[ct], 0, 0, 0);
            }
        }
        __builtin_amdgcn_s_setprio(0);

        #pragma unroll
        for (int ct = 0; ct < 2; ++ct) {
            #pragma unroll
            for (int r = 0; r < 4; ++r) {
                int i = 16 * w + g * 4 + r;
                if (i < NTOK) {
                    int d = ct * 16 + li;
                    qslot[i * 32 + d] = f2bf(o[ct][r]);   // P pre-normalized
                }
            }
        }

        if (it < 7) {
            if (tid < 392) {
                *(bf16x8*)&Ks[b ^ 1][krow][kseg] = kreg;
                #pragma unroll
                for (int j = 0; j < 8; ++j) Vt[b ^ 1][kseg + j][krow] = vreg[j];
            }
            aqc = aqn;
            qslot = qnext;
        }
    }
}

// ================= fallback (round-1) path =====================================
__global__ void k_bias(const float* __restrict__ table, const int* __restrict__ idx,
                       float* __restrict__ bias_full) {
    int h = blockIdx.x, i = blockIdx.y, j = threadIdx.x;
    if (j < NTOK)
        bias_full[(h * NTOK + i) * NTOK + j] = table[idx[i * NTOK + j] * 16 + h];
}

__global__ __launch_bounds__(256)
void k_qkv_old(const float* __restrict__ x, const float* __restrict__ w,
               const float* __restrict__ qb, unsigned short* __restrict__ qkvbuf) {
    __shared__ short As[128][36];
    __shared__ short Bs[128][36];
    const int tid = threadIdx.x;
    const int m0 = blockIdx.x * 128, n0 = blockIdx.y * 128;
    const int wid = tid >> 6, l = tid & 63;
    const int wr = wid >> 1, wc = wid & 1;
    const int g = l >> 4, li = l & 15;
    const int srow = tid >> 1, scol = (tid & 1) * 16;

    f32x4 acc[4][4] = {};
    const float* ap = x + (size_t)(m0 + srow) * DIMC + scol;
    const float* bp = w + (size_t)(n0 + srow) * DIMC + scol;

    for (int k0 = 0; k0 < DIMC; k0 += 32) {
        float4 a0 = *(const float4*)(ap + k0);
        float4 a1 = *(const float4*)(ap + k0 + 4);
        float4 a2 = *(const float4*)(ap + k0 + 8);
        float4 a3 = *(const float4*)(ap + k0 + 12);
        float4 b0 = *(const float4*)(bp + k0);
        float4 b1 = *(const float4*)(bp + k0 + 4);
        float4 b2 = *(const float4*)(bp + k0 + 8);
        float4 b3 = *(const float4*)(bp + k0 + 12);
        *(bf16x8*)&As[srow][scol]     = cvt8(a0, a1);
        *(bf16x8*)&As[srow][scol + 8] = cvt8(a2, a3);
        *(bf16x8*)&Bs[srow][scol]     = cvt8(b0, b1);
        *(bf16x8*)&Bs[srow][scol + 8] = cvt8(b2, b3);
        __syncthreads();
        bf16x8 af[4], bfr[4];
        #pragma unroll
        for (int mm = 0; mm < 4; ++mm)
            af[mm] = *(bf16x8*)&As[wr * 64 + mm * 16 + li][g * 8];
        #pragma unroll
        for (int nn = 0; nn < 4; ++nn)
            bfr[nn] = *(bf16x8*)&Bs[wc * 64 + nn * 16 + li][g * 8];
        #pragma unroll
        for (int mm = 0; mm < 4; ++mm)
            #pragma unroll
            for (int nn = 0; nn < 4; ++nn)
                acc[mm][nn] = __builtin_amdgcn_mfma_f32_16x16x32_bf16(
                    af[mm], bfr[nn], acc[mm][nn], 0, 0, 0);
        __syncthreads();
    }

    #pragma unroll
    for (int mm = 0; mm < 4; ++mm) {
        #pragma unroll
        for (int nn = 0; nn < 4; ++nn) {
            int col = n0 + wc * 64 + nn * 16 + li;
            int which = col >> 9;
            int h = (col >> 5) & 15;
            int d = col & 31;
            float bv = qb[col];
            #pragma unroll
            for (int r = 0; r < 4; ++r) {
                int row = m0 + wr * 64 + mm * 16 + g * 4 + r;
                unsigned bw = (unsigned)row / 98u;
                unsigned nn_ = (unsigned)row - bw * 98u;
                float v = acc[mm][nn][r] + bv;
                if (which == 0) v *= 0.17677669529663689f;
                qkvbuf[(size_t)((bw * 16u + h) * 3u + which) * 3136u + nn_ * 32u + d] =
                    f2bf(v);
            }
        }
    }
}

__global__ __launch_bounds__(448)
void k_attn_old(unsigned short* __restrict__ qkvbuf, const float* __restrict__ mask,
                const float* __restrict__ bias_full) {
    __shared__ short Ks[112][36];
    __shared__ short Vt[32][132];
    __shared__ short Ps[7][16][132];

    const int tid = threadIdx.x;
    const int w = tid >> 6, l = tid & 63, g = l >> 4, li = l & 15;
    const int bh = blockIdx.x;
    const int b = bh >> 4, h = bh & 15;

    unsigned short* qslot = qkvbuf + (size_t)bh * 3 * 3136;
    const unsigned short* kslot = qslot + 3136;
    const unsigned short* vslot = qslot + 6272;

    if (tid < 392) {
        int row = tid >> 2, seg = (tid & 3) * 8;
        bf16x8 kv = *(const bf16x8*)(kslot + row * 32 + seg);
        *(bf16x8*)&Ks[row][seg] = kv;
        bf16x8 vv = *(const bf16x8*)(vslot + row * 32 + seg);
        #pragma unroll
        for (int j = 0; j < 8; ++j) Vt[seg + j][row] = vv[j];
    }
    Ks[98 + (tid >> 5)][tid & 31] = 0;
    for (int t2 = tid; t2 < 32 * 34; t2 += 448) {
        int d = t2 / 34, c = t2 % 34;
        Vt[d][98 + c] = 0;
    }
    for (int t2 = l; t2 < 16 * 20; t2 += 64) {
        int r = t2 / 20, c = t2 % 20;
        Ps[w][r][112 + c] = 0;
    }

    bf16x8 aq = *(const bf16x8*)(qslot + (16 * w + li) * 32 + g * 8);

    __syncthreads();

    f32x4 s[7];
    #pragma unroll
    for (int j = 0; j < 7; ++j) {
        bf16x8 bk = *(bf16x8*)&Ks[16 * j + li][g * 8];
        f32x4 z = {};
        s[j] = __builtin_amdgcn_mfma_f32_16x16x32_bf16(aq, bk, z, 0, 0, 0);
    }

    const float* bp = bias_full + h * 9604;
    const float* mp = mask + (b & 63) * 9604;
    float sinv[4];
    #pragma unroll
    for (int r = 0; r < 4; ++r) {
        int i = 16 * w + g * 4 + r;
        bool rowok = (i < NTOK);
        float sv[7];
        float mx = -1e30f;
        #pragma unroll
        for (int j = 0; j < 7; ++j) {
            int col = 16 * j + li;
            float t = s[j][r];
            if (rowok && col < NTOK) t += bp[i * NTOK + col] + mp[i * NTOK + col];
            else t = -1e30f;
            sv[j] = t;
            mx = fmaxf(mx, t);
        }
        mx = fmaxf(mx, __shfl_xor(mx, 1));
        mx = fmaxf(mx, __shfl_xor(mx, 2));
        mx = fmaxf(mx, __shfl_xor(mx, 4));
        mx = fmaxf(mx, __shfl_xor(mx, 8));
        float sum = 0.f;
        #pragma unroll
        for (int j = 0; j < 7; ++j) {
            float p = __expf(sv[j] - mx);
            sum += p;
            Ps[w][g * 4 + r][16 * j + li] = (short)f2bf(p);
        }
        sum += __shfl_xor(sum, 1);
        sum += __shfl_xor(sum, 2);
        sum += __shfl_xor(sum, 4);
        sum += __shfl_xor(sum, 8);
        sinv[r] = 1.0f / sum;
    }

    __syncthreads();

    f32x4 o[2] = {};
    #pragma unroll
    for (int ks = 0; ks < 4; ++ks) {
        bf16x8 pa = *(bf16x8*)&Ps[w][li][ks * 32 + g * 8];
        #pragma unroll
        for (int ct = 0; ct < 2; ++ct) {
            bf16x8 vb = *(bf16x8*)&Vt[ct * 16 + li][ks * 32 + g * 8];
            o[ct] = __builtin_amdgcn_mfma_f32_16x16x32_bf16(pa, vb, o[ct], 0, 0, 0);
        }
    }

    #pragma unroll
    for (int ct = 0; ct < 2; ++ct) {
        #pragma unroll
        for (int r = 0; r < 4; ++r) {
            int i = 16 * w + g * 4 + r;
            if (i < NTOK) {
                int d = ct * 16 + li;
                qslot[i * 32 + d] = f2bf(o[ct][r] * sinv[r]);
            }
        }
    }
}

__global__ __launch_bounds__(256)
void k_proj_old(const unsigned short* __restrict__ qkvbuf, const float* __restrict__ w,
                const float* __restrict__ pb, float* __restrict__ out) {
    __shared__ short As[128][36];
    __shared__ short Bs[128][36];
    const int tid = threadIdx.x;
    const int m0 = blockIdx.x * 128, n0 = blockIdx.y * 128;
    const int wid = tid >> 6, l = tid & 63;
    const int wr = wid >> 1, wc = wid & 1;
    const int g = l >> 4, li = l & 15;
    const int srow = tid >> 1, scol = (tid & 1) * 16;

    unsigned row = m0 + srow;
    unsigned bw = row / 98u, nn_ = row - bw * 98u;
    const unsigned short* abase =
        qkvbuf + (size_t)bw * 48u * 3136u + (size_t)nn_ * 32u + scol;
    const float* bp = w + (size_t)(n0 + srow) * DIMC + scol;

    f32x4 acc[4][4] = {};

    for (int k0 = 0; k0 < DIMC; k0 += 32) {
        int hh = k0 >> 5;
        const unsigned short* ap = abase + (size_t)hh * 9408u;
        bf16x8 A0 = *(const bf16x8*)ap;
        bf16x8 A1 = *(const bf16x8*)(ap + 8);
        float4 b0 = *(const float4*)(bp + k0);
        float4 b1 = *(const float4*)(bp + k0 + 4);
        float4 b2 = *(const float4*)(bp + k0 + 8);
        float4 b3 = *(const float4*)(bp + k0 + 12);
        *(bf16x8*)&As[srow][scol]     = A0;
        *(bf16x8*)&As[srow][scol + 8] = A1;
        *(bf16x8*)&Bs[srow][scol]     = cvt8(b0, b1);
        *(bf16x8*)&Bs[srow][scol + 8] = cvt8(b2, b3);
        __syncthreads();
        bf16x8 af[4], bfr[4];
        #pragma unroll
        for (int mm = 0; mm < 4; ++mm)
            af[mm] = *(bf16x8*)&As[wr * 64 + mm * 16 + li][g * 8];
        #pragma unroll
        for (int nn = 0; nn < 4; ++nn)
            bfr[nn] = *(bf16x8*)&Bs[wc * 64 + nn * 16 + li][g * 8];
        #pragma unroll
        for (int mm = 0; mm < 4; ++mm)
            #pragma unroll
            for (int nn = 0; nn < 4; ++nn)
                acc[mm][nn] = __builtin_amdgcn_mfma_f32_16x16x32_bf16(
                    af[mm], bfr[nn], acc[mm][nn], 0, 0, 0);
        __syncthreads();
    }

    #pragma unroll
    for (int mm = 0; mm < 4; ++mm) {
        #pragma unroll
        for (int nn = 0; nn < 4; ++nn) {
            int col = n0 + wc * 64 + nn * 16 + li;
            float bv = pb[col];
            #pragma unroll
            for (int r = 0; r < 4; ++r) {
                int row2 = m0 + wr * 64 + mm * 16 + g * 4 + r;
                out[(size_t)row2 * DIMC + col] = acc[mm][nn][r] + bv;
            }
        }
    }
}

extern "C" void kernel_launch(void* const* d_in, const int* in_sizes, int n_in,
                              void* d_out, int out_size, void* d_ws, size_t ws_size,
                              hipStream_t stream) {
    const float* x          = (const float*)d_in[0];
    const float* mask       = (const float*)d_in[1];
    const float* qkv_w      = (const float*)d_in[2];
    const float* qkv_b      = (const float*)d_in[3];
    const float* proj_w     = (const float*)d_in[4];
    const float* proj_b     = (const float*)d_in[5];
    const float* bias_table = (const float*)d_in[6];
    const int*   rel_idx    = (const int*)d_in[7];
    float* out = (float*)d_out;

    const size_t QKV_BYTES = (size_t)16384 * 3 * 3136 * 2;   // 308,281,344
    const size_t XB_BYTES  = (size_t)100352 * 512 * 2;       // 102,760,448
    const size_t WQ_BYTES  = (size_t)1536 * 512 * 2;
    const size_t WP_BYTES  = (size_t)512 * 512 * 2;

    unsigned short* qkvbuf = (unsigned short*)d_ws;
    const size_t need = QKV_BYTES + XB_BYTES + WQ_BYTES + WP_BYTES;

    if (ws_size >= need) {
        unsigned short* xb  = (unsigned short*)((char*)d_ws + QKV_BYTES);
        unsigned short* wqb = xb + (size_t)100352 * 512;
        unsigned short* wpb = wqb + (size_t)1536 * 512;
        float* bm_t = (float*)xb;   // alias: xb dead after k_qkv4 (51.4MB < 102.8MB)

        k_cvt3<<<dim3(25600), dim3(256), 0, stream>>>(x, xb, qkv_w, wqb, proj_w, wpb);

        k_qkv4<<<dim3(9408), dim3(256), 0, stream>>>(xb, wqb, qkv_b, qkvbuf);
        k_bm2<<<dim3(1024), dim3(256), 0, stream>>>(bias_table, rel_idx, mask, bm_t);
        k_attn4<<<dim3(2048), dim3(448), 0, stream>>>(qkvbuf, bm_t);
        k_proj4<<<dim3(3136), dim3(256), 0, stream>>>(qkvbuf, wpb, proj_b, out);
    } else {
        float* bias_full = (float*)((char*)d_ws + QKV_BYTES);
        k_bias<<<dim3(16, 98), dim3(128), 0, stream>>>(bias_table, rel_idx, bias_full);
        k_qkv_old<<<dim3(784, 12), dim3(256), 0, stream>>>(x, qkv_w, qkv_b, qkvbuf);
        k_attn_old<<<dim3(16384), dim3(448), 0, stream>>>(qkvbuf, mask, bias_full);
        k_proj_old<<<dim3(784, 4), dim3(256), 0, stream>>>(qkvbuf, proj_w, proj_b, out);
    }
}

// Round 16
// 545.470 us; speedup vs baseline: 1.0835x; 1.0835x over previous
//
#include <hip/hip_runtime.h>
#include <hip/hip_bf16.h>
#include <stdint.h>

#define DIMC 512
#define NTOK 98
// M_TOTAL = 1024*98 = 100352 = 392 * 256

typedef float f32x4 __attribute__((ext_vector_type(4)));
typedef short bf16x8 __attribute__((ext_vector_type(8)));
typedef short bf16x4 __attribute__((ext_vector_type(4)));

__device__ inline unsigned short f2bf(float f) {
    union { float f; uint32_t u; } v; v.f = f;
    uint32_t r = v.u + 0x7fffu + ((v.u >> 16) & 1u);
    return (unsigned short)(r >> 16);
}

__device__ inline bf16x8 cvt8(float4 a, float4 b) {
    bf16x8 r;
    r[0] = (short)f2bf(a.x); r[1] = (short)f2bf(a.y);
    r[2] = (short)f2bf(a.z); r[3] = (short)f2bf(a.w);
    r[4] = (short)f2bf(b.x); r[5] = (short)f2bf(b.y);
    r[6] = (short)f2bf(b.z); r[7] = (short)f2bf(b.w);
    return r;
}

__device__ __forceinline__ void gload16(const void* g, void* l) {
    __builtin_amdgcn_global_load_lds(
        (const __attribute__((address_space(1))) unsigned int*)g,
        (__attribute__((address_space(3))) unsigned int*)l, 16, 0, 0);
}

#define CFENCE() __asm__ __volatile__("" ::: "memory")
#define BARRIER() do { CFENCE(); __builtin_amdgcn_s_barrier(); CFENCE(); } while (0)

// ---------------- fused fp32 -> bf16 convert for x, qkv_w, proj_w --------------
__global__ void k_cvt3(const float* __restrict__ s0, unsigned short* __restrict__ d0,
                       const float* __restrict__ s1, unsigned short* __restrict__ d1,
                       const float* __restrict__ s2, unsigned short* __restrict__ d2) {
    int b = blockIdx.x;
    const float* src; unsigned short* dst; int i;
    if (b < 25088)      { src = s0; dst = d0; i = b * 256 + threadIdx.x; }
    else if (b < 25472) { src = s1; dst = d1; i = (b - 25088) * 256 + threadIdx.x; }
    else                { src = s2; dst = d2; i = (b - 25472) * 256 + threadIdx.x; }
    float4 a = *(const float4*)(src + (size_t)i * 8);
    float4 c = *(const float4*)(src + (size_t)i * 8 + 4);
    *(bf16x8*)(dst + (size_t)i * 8) = cvt8(a, c);
}

// -------- combined bias+mask, TRANSPOSED for swapped QK^T: [slice][i:112][c:112]
__global__ void k_bm2(const float* __restrict__ table, const int* __restrict__ idx,
                      const float* __restrict__ mask, float* __restrict__ bm_t) {
    int slice = blockIdx.x;            // 0..1023 = b64*16 + h
    int b64 = slice >> 4, h = slice & 15;
    float* dst = bm_t + (size_t)slice * 12544;   // 112*112
    const float* mp = mask + (size_t)b64 * 9604;
    for (int t = threadIdx.x; t < 12544; t += blockDim.x) {
        int i = t / 112, c = t - i * 112;
        float v = -1e9f;
        if (c < NTOK && i < NTOK)
            v = (table[idx[i * NTOK + c] * 16 + h] + mp[i * NTOK + c])
                * 1.4426950408889634f;
        dst[t] = v;
    }
}

// ============ qkv GEMM: 256^2, BK=64, 8 waves, 8-phase, ONE barrier per phase ===
__global__ __launch_bounds__(512, 2)
void k_qkv3(const unsigned short* __restrict__ xb, const unsigned short* __restrict__ wb,
            const float* __restrict__ qb, unsigned short* __restrict__ qkvbuf) {
    __shared__ unsigned short As[2][2][128 * 64];   // [slot][half][row*64 + col]
    __shared__ unsigned short Bs[2][2][128 * 64];
    const int tid = threadIdx.x;
    const int wid = tid >> 6, l = tid & 63, g = l >> 4, li = l & 15;
    const int wm = wid >> 2, wn = wid & 3;
    const int id = blockIdx.x;                     // 2352 = 8 * 49 * 6
    const int xcd = id & 7, local = id >> 3;
    const int mt = xcd * 49 + local / 6;
    const int nt = local - (local / 6) * 6;
    const int m0 = mt * 256, n0 = nt * 256;

    const int srow = tid >> 3;
    const int scg  = tid & 7;
    const int sxor = (scg ^ (srow & 7)) * 8;       // elems
    const unsigned short* aG[2][2];
    const unsigned short* bG[2][2];
    #pragma unroll
    for (int h = 0; h < 2; ++h) {
        aG[h][0] = xb + (size_t)(m0 + h * 128 + srow) * DIMC + sxor;
        aG[h][1] = xb + (size_t)(m0 + h * 128 + 64 + srow) * DIMC + sxor;
        bG[h][0] = wb + (size_t)(n0 + h * 128 + srow) * DIMC + sxor;
        bG[h][1] = wb + (size_t)(n0 + h * 128 + 64 + srow) * DIMC + sxor;
    }
    const int lb0 = wid * 512;          // chunk-set 0 (rows 0-63 of a half)
    const int lb1 = 4096 + wid * 512;   // chunk-set 1 (rows 64-127)

    const int axor0 = ((0 + g) ^ (li & 7)) * 8;
    const int axor1 = ((4 + g) ^ (li & 7)) * 8;
    const int arow = li * 64;
    const int brow = (wn & 1) * 4096 + li * 64;
    const int bh = wn >> 1;

    f32x4 acc[8][4] = {};

    // prologue: tile 0, pairs in order b0, b1, a0, a1
    gload16(bG[0][0], &Bs[0][0][lb0]); gload16(bG[1][0], &Bs[0][1][lb0]);
    gload16(bG[0][1], &Bs[0][0][lb1]); gload16(bG[1][1], &Bs[0][1][lb1]);
    gload16(aG[0][0], &As[0][0][lb0]); gload16(aG[1][0], &As[0][1][lb0]);
    gload16(aG[0][1], &As[0][0][lb1]); gload16(aG[1][1], &As[0][1][lb1]);

    #pragma unroll
    for (int kt = 0; kt < 8; ++kt) {
        const int s = kt & 1, p = s ^ 1;
        const int ko = (kt + 1) * 64;
        bf16x8 bfr[4][2];
        #pragma unroll
        for (int q = 0; q < 4; ++q) {
            const int mq0 = 2 * q;
            bf16x8 a00, a01, a10, a11;
            if (q == 1 || q == 3) {  // pre-barrier: retired by earlier own-wave wait
                a00 = *(const bf16x8*)&As[s][wm][arow + mq0 * 1024 + axor0];
                a01 = *(const bf16x8*)&As[s][wm][arow + mq0 * 1024 + axor1];
                a10 = *(const bf16x8*)&As[s][wm][arow + (mq0 + 1) * 1024 + axor0];
                a11 = *(const bf16x8*)&As[s][wm][arow + (mq0 + 1) * 1024 + axor1];
            }
            if (kt < 7) {
                if (q == 0) { gload16(bG[0][0] + ko, &Bs[p][0][lb0]);
                              gload16(bG[1][0] + ko, &Bs[p][1][lb0]); }
                if (q == 1) { gload16(bG[0][1] + ko, &Bs[p][0][lb1]);
                              gload16(bG[1][1] + ko, &Bs[p][1][lb1]); }
                if (q == 2) { gload16(aG[0][0] + ko, &As[p][0][lb0]);
                              gload16(aG[1][0] + ko, &As[p][1][lb0]); }
                if (q == 3) { gload16(aG[0][1] + ko, &As[p][0][lb1]);
                              gload16(aG[1][1] + ko, &As[p][1][lb1]); }
            }
            if (q == 0) {
                if (kt < 7) __asm__ __volatile__("s_waitcnt vmcnt(4)" ::: "memory");
                else        __asm__ __volatile__("s_waitcnt vmcnt(2)" ::: "memory");
            } else if (q == 2) {
                if (kt < 7) __asm__ __volatile__("s_waitcnt vmcnt(6)" ::: "memory");
                else        __asm__ __volatile__("s_waitcnt vmcnt(0)" ::: "memory");
            } else {
                if (kt < 7) __asm__ __volatile__("s_waitcnt vmcnt(6)" ::: "memory");
            }
            BARRIER();   // single barrier per phase
            if (q == 0) {
                #pragma unroll
                for (int nq = 0; nq < 4; ++nq) {
                    bfr[nq][0] = *(const bf16x8*)&Bs[s][bh][brow + nq * 1024 + axor0];
                    bfr[nq][1] = *(const bf16x8*)&Bs[s][bh][brow + nq * 1024 + axor1];
                }
            }
            if (q == 0 || q == 2) {  // post-barrier: retired by THIS phase's wait
                a00 = *(const bf16x8*)&As[s][wm][arow + mq0 * 1024 + axor0];
                a01 = *(const bf16x8*)&As[s][wm][arow + mq0 * 1024 + axor1];
                a10 = *(const bf16x8*)&As[s][wm][arow + (mq0 + 1) * 1024 + axor0];
                a11 = *(const bf16x8*)&As[s][wm][arow + (mq0 + 1) * 1024 + axor1];
            }
            __asm__ __volatile__("s_waitcnt lgkmcnt(0)" ::: "memory");
            __builtin_amdgcn_s_setprio(1);
            #pragma unroll
            for (int nq = 0; nq < 4; ++nq) {
                acc[mq0][nq] = __builtin_amdgcn_mfma_f32_16x16x32_bf16(
                    bfr[nq][0], a00, acc[mq0][nq], 0, 0, 0);
                acc[mq0][nq] = __builtin_amdgcn_mfma_f32_16x16x32_bf16(
                    bfr[nq][1], a01, acc[mq0][nq], 0, 0, 0);
                acc[mq0 + 1][nq] = __builtin_amdgcn_mfma_f32_16x16x32_bf16(
                    bfr[nq][0], a10, acc[mq0 + 1][nq], 0, 0, 0);
                acc[mq0 + 1][nq] = __builtin_amdgcn_mfma_f32_16x16x32_bf16(
                    bfr[nq][1], a11, acc[mq0 + 1][nq], 0, 0, 0);
            }
            __builtin_amdgcn_s_setprio(0);
        }
    }

    // epilogue: swapped layout -> thread's quad = row (m=li) x 4 consecutive cols
    #pragma unroll
    for (int mq = 0; mq < 8; ++mq) {
        int row = m0 + wm * 128 + mq * 16 + li;
        unsigned bw = (unsigned)row / 98u;
        unsigned nn_ = (unsigned)row - bw * 98u;
        unsigned short* rbase = qkvbuf + (size_t)bw * 150528u + nn_ * 32u;
        #pragma unroll
        for (int nq = 0; nq < 4; ++nq) {
            int col0 = n0 + wn * 64 + nq * 16 + g * 4;
            int which = col0 >> 9;
            int h = (col0 >> 5) & 15;
            int d0 = col0 & 31;
            float4 bv = *(const float4*)(qb + col0);
            float sc = (which == 0)
                ? (0.17677669529663689f * 1.4426950408889634f) : 1.0f;
            bf16x4 pk;
            pk[0] = (short)f2bf((acc[mq][nq][0] + bv.x) * sc);
            pk[1] = (short)f2bf((acc[mq][nq][1] + bv.y) * sc);
            pk[2] = (short)f2bf((acc[mq][nq][2] + bv.z) * sc);
            pk[3] = (short)f2bf((acc[mq][nq][3] + bv.w) * sc);
            *(bf16x4*)(rbase + (size_t)(h * 3 + which) * 3136u + d0) = pk;
        }
    }
}

// ============ proj GEMM: same 8-phase single-barrier pipeline, A gathered ======
__global__ __launch_bounds__(512, 2)
void k_proj3(const unsigned short* __restrict__ qkvbuf,
             const unsigned short* __restrict__ wb,
             const float* __restrict__ pb, float* __restrict__ out) {
    __shared__ unsigned short As[2][2][128 * 64];
    __shared__ unsigned short Bs[2][2][128 * 64];
    const int tid = threadIdx.x;
    const int wid = tid >> 6, l = tid & 63, g = l >> 4, li = l & 15;
    const int wm = wid >> 2, wn = wid & 3;
    const int id = blockIdx.x;                     // 784 = 8 * 49 * 2
    const int xcd = id & 7, local = id >> 3;
    const int mt = xcd * 49 + local / 2;
    const int nt = local & 1;
    const int m0 = mt * 256, n0 = nt * 256;

    const int srow = tid >> 3;
    const int scg  = tid & 7;
    const int cgx  = scg ^ (srow & 7);
    const unsigned short* aG[2][2];
    const unsigned short* bG[2][2];
    #pragma unroll
    for (int h = 0; h < 2; ++h) {
        #pragma unroll
        for (int i = 0; i < 2; ++i) {
            int R = m0 + h * 128 + i * 64 + srow;
            unsigned bw = (unsigned)R / 98u, nn = (unsigned)R - bw * 98u;
            aG[h][i] = qkvbuf + (size_t)bw * 150528u + nn * 32u
                       + (size_t)(cgx >> 2) * 9408u + (cgx & 3) * 8;
            bG[h][i] = wb + (size_t)(n0 + h * 128 + i * 64 + srow) * DIMC + cgx * 8;
        }
    }
    const int lb0 = wid * 512;
    const int lb1 = 4096 + wid * 512;

    const int axor0 = ((0 + g) ^ (li & 7)) * 8;
    const int axor1 = ((4 + g) ^ (li & 7)) * 8;
    const int arow = li * 64;
    const int brow = (wn & 1) * 4096 + li * 64;
    const int bh = wn >> 1;

    f32x4 acc[8][4] = {};

    gload16(bG[0][0], &Bs[0][0][lb0]); gload16(bG[1][0], &Bs[0][1][lb0]);
    gload16(bG[0][1], &Bs[0][0][lb1]); gload16(bG[1][1], &Bs[0][1][lb1]);
    gload16(aG[0][0], &As[0][0][lb0]); gload16(aG[1][0], &As[0][1][lb0]);
    gload16(aG[0][1], &As[0][0][lb1]); gload16(aG[1][1], &As[0][1][lb1]);

    #pragma unroll
    for (int kt = 0; kt < 8; ++kt) {
        const int s = kt & 1, p = s ^ 1;
        const size_t ao = (size_t)(kt + 1) * 18816u;
        const int ko = (kt + 1) * 64;
        bf16x8 bfr[4][2];
        #pragma unroll
        for (int q = 0; q < 4; ++q) {
            const int mq0 = 2 * q;
            bf16x8 a00, a01, a10, a11;
            if (q == 1 || q == 3) {
                a00 = *(const bf16x8*)&As[s][wm][arow + mq0 * 1024 + axor0];
                a01 = *(const bf16x8*)&As[s][wm][arow + mq0 * 1024 + axor1];
                a10 = *(const bf16x8*)&As[s][wm][arow + (mq0 + 1) * 1024 + axor0];
                a11 = *(const bf16x8*)&As[s][wm][arow + (mq0 + 1) * 1024 + axor1];
            }
            if (kt < 7) {
                if (q == 0) { gload16(bG[0][0] + ko, &Bs[p][0][lb0]);
                              gload16(bG[1][0] + ko, &Bs[p][1][lb0]); }
                if (q == 1) { gload16(bG[0][1] + ko, &Bs[p][0][lb1]);
                              gload16(bG[1][1] + ko, &Bs[p][1][lb1]); }
                if (q == 2) { gload16(aG[0][0] + ao, &As[p][0][lb0]);
                              gload16(aG[1][0] + ao, &As[p][1][lb0]); }
                if (q == 3) { gload16(aG[0][1] + ao, &As[p][0][lb1]);
                              gload16(aG[1][1] + ao, &As[p][1][lb1]); }
            }
            if (q == 0) {
                if (kt < 7) __asm__ __volatile__("s_waitcnt vmcnt(4)" ::: "memory");
                else        __asm__ __volatile__("s_waitcnt vmcnt(2)" ::: "memory");
            } else if (q == 2) {
                if (kt < 7) __asm__ __volatile__("s_waitcnt vmcnt(6)" ::: "memory");
                else        __asm__ __volatile__("s_waitcnt vmcnt(0)" ::: "memory");
            } else {
                if (kt < 7) __asm__ __volatile__("s_waitcnt vmcnt(6)" ::: "memory");
            }
            BARRIER();
            if (q == 0) {
                #pragma unroll
                for (int nq = 0; nq < 4; ++nq) {
                    bfr[nq][0] = *(const bf16x8*)&Bs[s][bh][brow + nq * 1024 + axor0];
                    bfr[nq][1] = *(const bf16x8*)&Bs[s][bh][brow + nq * 1024 + axor1];
                }
            }
            if (q == 0 || q == 2) {
                a00 = *(const bf16x8*)&As[s][wm][arow + mq0 * 1024 + axor0];
                a01 = *(const bf16x8*)&As[s][wm][arow + mq0 * 1024 + axor1];
                a10 = *(const bf16x8*)&As[s][wm][arow + (mq0 + 1) * 1024 + axor0];
                a11 = *(const bf16x8*)&As[s][wm][arow + (mq0 + 1) * 1024 + axor1];
            }
            __asm__ __volatile__("s_waitcnt lgkmcnt(0)" ::: "memory");
            __builtin_amdgcn_s_setprio(1);
            #pragma unroll
            for (int nq = 0; nq < 4; ++nq) {
                acc[mq0][nq] = __builtin_amdgcn_mfma_f32_16x16x32_bf16(
                    bfr[nq][0], a00, acc[mq0][nq], 0, 0, 0);
                acc[mq0][nq] = __builtin_amdgcn_mfma_f32_16x16x32_bf16(
                    bfr[nq][1], a01, acc[mq0][nq], 0, 0, 0);
                acc[mq0 + 1][nq] = __builtin_amdgcn_mfma_f32_16x16x32_bf16(
                    bfr[nq][0], a10, acc[mq0 + 1][nq], 0, 0, 0);
                acc[mq0 + 1][nq] = __builtin_amdgcn_mfma_f32_16x16x32_bf16(
                    bfr[nq][1], a11, acc[mq0 + 1][nq], 0, 0, 0);
            }
            __builtin_amdgcn_s_setprio(0);
        }
    }

    #pragma unroll
    for (int mq = 0; mq < 8; ++mq) {
        int row2 = m0 + wm * 128 + mq * 16 + li;
        float* orow = out + (size_t)row2 * DIMC;
        #pragma unroll
        for (int nq = 0; nq < 4; ++nq) {
            int col0 = n0 + wn * 64 + nq * 16 + g * 4;
            float4 bv = *(const float4*)(pb + col0);
            float4 v;
            v.x = acc[mq][nq][0] + bv.x;
            v.y = acc[mq][nq][1] + bv.y;
            v.z = acc[mq][nq][2] + bv.z;
            v.w = acc[mq][nq][3] + bv.w;
            *(float4*)(orow + col0) = v;
        }
    }
}

// ------- attention: persistent, dbuf K/V, SWAPPED QK^T (S^T = K x Q) -----------
__global__ __launch_bounds__(448)
void k_attn4(unsigned short* __restrict__ qkvbuf, const float* __restrict__ bm_t) {
    __shared__ short Ks[2][112][36];
    __shared__ short Vt[2][32][132];
    __shared__ short Ps[7][16][132];   // [wave][q-row][k]; k 112..127 zeroed once

    const int tid = threadIdx.x;
    const int w = tid >> 6, l = tid & 63, g = l >> 4, li = l & 15;

    const int id = blockIdx.x;                 // 2048
    const int slice = id >> 1, mh = id & 1;    // slice = (b%64)*16 + h

    const float* bmp = bm_t + (size_t)slice * 12544 + (16 * w + li) * 112 + g * 4;
    f32x4 bmf[7];
    #pragma unroll
    for (int j = 0; j < 7; ++j)
        bmf[j] = *(const f32x4*)(bmp + 16 * j);

    #pragma unroll
    for (int bsel = 0; bsel < 2; ++bsel) {
        Ks[bsel][98 + (tid >> 5)][tid & 31] = 0;
        for (int t2 = tid; t2 < 32 * 34; t2 += 448) {
            int d = t2 / 34, c = t2 % 34;
            Vt[bsel][d][98 + c] = 0;
        }
    }
    {
        bf16x4 z = {};
        *(bf16x4*)&Ps[w][li][112 + g * 4] = z;
    }

    const int krow = tid >> 2, kseg = (tid & 3) * 8;
    const size_t step = (size_t)1024 * 9408;
    unsigned short* qslot = qkvbuf + (size_t)(mh * 8192 + slice) * 9408;

    bf16x8 kreg = {}, vreg = {}, aqc, aqn;
    if (tid < 392) {
        kreg = *(const bf16x8*)(qslot + 3136 + krow * 32 + kseg);
        vreg = *(const bf16x8*)(qslot + 6272 + krow * 32 + kseg);
    }
    aqc = *(const bf16x8*)(qslot + (16 * w + li) * 32 + g * 8);
    if (tid < 392) {
        *(bf16x8*)&Ks[0][krow][kseg] = kreg;
        #pragma unroll
        for (int j = 0; j < 8; ++j) Vt[0][kseg + j][krow] = vreg[j];
    }

    for (int it = 0; it < 8; ++it) {
        const int b = it & 1;
        __syncthreads();   // buf b staged visible

        unsigned short* qnext = qslot + step;
        if (it < 7) {
            if (tid < 392) {
                kreg = *(const bf16x8*)(qnext + 3136 + krow * 32 + kseg);
                vreg = *(const bf16x8*)(qnext + 6272 + krow * 32 + kseg);
            }
            aqn = *(const bf16x8*)(qnext + (16 * w + li) * 32 + g * 8);
        }

        // S^T = K @ Q^T + bias^T: lane holds S[q=li][k=16j+g*4+r]
        f32x4 s[7];
        __builtin_amdgcn_s_setprio(1);
        #pragma unroll
        for (int j = 0; j < 7; ++j) {
            bf16x8 bk = *(bf16x8*)&Ks[b][16 * j + li][g * 8];
            s[j] = __builtin_amdgcn_mfma_f32_16x16x32_bf16(bk, aqc, bmf[j], 0, 0, 0);
        }
        __builtin_amdgcn_s_setprio(0);

        float p[7][4];
        float sum = 0.f;
        #pragma unroll
        for (int j = 0; j < 7; ++j)
            #pragma unroll
            for (int r = 0; r < 4; ++r) {
                p[j][r] = exp2f(s[j][r]);
                sum += p[j][r];
            }
        sum += __shfl_xor(sum, 16);
        sum += __shfl_xor(sum, 32);
        float sinv = 1.0f / sum;

        #pragma unroll
        for (int j = 0; j < 7; ++j) {
            bf16x4 pk;
            pk[0] = (short)f2bf(p[j][0] * sinv);
            pk[1] = (short)f2bf(p[j][1] * sinv);
            pk[2] = (short)f2bf(p[j][2] * sinv);
            pk[3] = (short)f2bf(p[j][3] * sinv);
            *(bf16x4*)&Ps[w][li][16 * j + g * 4] = pk;
        }

        __asm__ __volatile__("s_waitcnt lgkmcnt(0)" ::: "memory");
        __builtin_amdgcn_sched_barrier(0);

        f32x4 o[2] = {};
        __builtin_amdgcn_s_setprio(1);
        #pragma unroll
        for (int ks = 0; ks < 4; ++ks) {
            bf16x8 pa = *(bf16x8*)&Ps[w][li][ks * 32 + g * 8];
            #pragma unroll
            for (int ct = 0; ct < 2; ++ct) {
                bf16x8 vb = *(bf16x8*)&Vt[b][ct * 16 + li][ks * 32 + g * 8];
                o[ct] = __builtin_amdgcn_mfma_f32_16x16x32_bf16(pa, vb, o[ct], 0, 0, 0);
            }
        }
        __builtin_amdgcn_s_setprio(0);

        #pragma unroll
        for (int ct = 0; ct < 2; ++ct) {
            #pragma unroll
            for (int r = 0; r < 4; ++r) {
                int i = 16 * w + g * 4 + r;
                if (i < NTOK) {
                    int d = ct * 16 + li;
                    qslot[i * 32 + d] = f2bf(o[ct][r]);   // P pre-normalized
                }
            }
        }

        if (it < 7) {
            if (tid < 392) {
                *(bf16x8*)&Ks[b ^ 1][krow][kseg] = kreg;
                #pragma unroll
                for (int j = 0; j < 8; ++j) Vt[b ^ 1][kseg + j][krow] = vreg[j];
            }
            aqc = aqn;
            qslot = qnext;
        }
    }
}

// ================= fallback (round-1) path =====================================
__global__ void k_bias(const float* __restrict__ table, const int* __restrict__ idx,
                       float* __restrict__ bias_full) {
    int h = blockIdx.x, i = blockIdx.y, j = threadIdx.x;
    if (j < NTOK)
        bias_full[(h * NTOK + i) * NTOK + j] = table[idx[i * NTOK + j] * 16 + h];
}

__global__ __launch_bounds__(256)
void k_qkv_old(const float* __restrict__ x, const float* __restrict__ w,
               const float* __restrict__ qb, unsigned short* __restrict__ qkvbuf) {
    __shared__ short As[128][36];
    __shared__ short Bs[128][36];
    const int tid = threadIdx.x;
    const int m0 = blockIdx.x * 128, n0 = blockIdx.y * 128;
    const int wid = tid >> 6, l = tid & 63;
    const int wr = wid >> 1, wc = wid & 1;
    const int g = l >> 4, li = l & 15;
    const int srow = tid >> 1, scol = (tid & 1) * 16;

    f32x4 acc[4][4] = {};
    const float* ap = x + (size_t)(m0 + srow) * DIMC + scol;
    const float* bp = w + (size_t)(n0 + srow) * DIMC + scol;

    for (int k0 = 0; k0 < DIMC; k0 += 32) {
        float4 a0 = *(const float4*)(ap + k0);
        float4 a1 = *(const float4*)(ap + k0 + 4);
        float4 a2 = *(const float4*)(ap + k0 + 8);
        float4 a3 = *(const float4*)(ap + k0 + 12);
        float4 b0 = *(const float4*)(bp + k0);
        float4 b1 = *(const float4*)(bp + k0 + 4);
        float4 b2 = *(const float4*)(bp + k0 + 8);
        float4 b3 = *(const float4*)(bp + k0 + 12);
        *(bf16x8*)&As[srow][scol]     = cvt8(a0, a1);
        *(bf16x8*)&As[srow][scol + 8] = cvt8(a2, a3);
        *(bf16x8*)&Bs[srow][scol]     = cvt8(b0, b1);
        *(bf16x8*)&Bs[srow][scol + 8] = cvt8(b2, b3);
        __syncthreads();
        bf16x8 af[4], bfr[4];
        #pragma unroll
        for (int mm = 0; mm < 4; ++mm)
            af[mm] = *(bf16x8*)&As[wr * 64 + mm * 16 + li][g * 8];
        #pragma unroll
        for (int nn = 0; nn < 4; ++nn)
            bfr[nn] = *(bf16x8*)&Bs[wc * 64 + nn * 16 + li][g * 8];
        #pragma unroll
        for (int mm = 0; mm < 4; ++mm)
            #pragma unroll
            for (int nn = 0; nn < 4; ++nn)
                acc[mm][nn] = __builtin_amdgcn_mfma_f32_16x16x32_bf16(
                    af[mm], bfr[nn], acc[mm][nn], 0, 0, 0);
        __syncthreads();
    }

    #pragma unroll
    for (int mm = 0; mm < 4; ++mm) {
        #pragma unroll
        for (int nn = 0; nn < 4; ++nn) {
            int col = n0 + wc * 64 + nn * 16 + li;
            int which = col >> 9;
            int h = (col >> 5) & 15;
            int d = col & 31;
            float bv = qb[col];
            #pragma unroll
            for (int r = 0; r < 4; ++r) {
                int row = m0 + wr * 64 + mm * 16 + g * 4 + r;
                unsigned bw = (unsigned)row / 98u;
                unsigned nn_ = (unsigned)row - bw * 98u;
                float v = acc[mm][nn][r] + bv;
                if (which == 0) v *= 0.17677669529663689f;
                qkvbuf[(size_t)((bw * 16u + h) * 3u + which) * 3136u + nn_ * 32u + d] =
                    f2bf(v);
            }
        }
    }
}

__global__ __launch_bounds__(448)
void k_attn_old(unsigned short* __restrict__ qkvbuf, const float* __restrict__ mask,
                const float* __restrict__ bias_full) {
    __shared__ short Ks[112][36];
    __shared__ short Vt[32][132];
    __shared__ short Ps[7][16][132];

    const int tid = threadIdx.x;
    const int w = tid >> 6, l = tid & 63, g = l >> 4, li = l & 15;
    const int bh = blockIdx.x;
    const int b = bh >> 4, h = bh & 15;

    unsigned short* qslot = qkvbuf + (size_t)bh * 3 * 3136;
    const unsigned short* kslot = qslot + 3136;
    const unsigned short* vslot = qslot + 6272;

    if (tid < 392) {
        int row = tid >> 2, seg = (tid & 3) * 8;
        bf16x8 kv = *(const bf16x8*)(kslot + row * 32 + seg);
        *(bf16x8*)&Ks[row][seg] = kv;
        bf16x8 vv = *(const bf16x8*)(vslot + row * 32 + seg);
        #pragma unroll
        for (int j = 0; j < 8; ++j) Vt[seg + j][row] = vv[j];
    }
    Ks[98 + (tid >> 5)][tid & 31] = 0;
    for (int t2 = tid; t2 < 32 * 34; t2 += 448) {
        int d = t2 / 34, c = t2 % 34;
        Vt[d][98 + c] = 0;
    }
    for (int t2 = l; t2 < 16 * 20; t2 += 64) {
        int r = t2 / 20, c = t2 % 20;
        Ps[w][r][112 + c] = 0;
    }

    bf16x8 aq = *(const bf16x8*)(qslot + (16 * w + li) * 32 + g * 8);

    __syncthreads();

    f32x4 s[7];
    #pragma unroll
    for (int j = 0; j < 7; ++j) {
        bf16x8 bk = *(bf16x8*)&Ks[16 * j + li][g * 8];
        f32x4 z = {};
        s[j] = __builtin_amdgcn_mfma_f32_16x16x32_bf16(aq, bk, z, 0, 0, 0);
    }

    const float* bp = bias_full + h * 9604;
    const float* mp = mask + (b & 63) * 9604;
    float sinv[4];
    #pragma unroll
    for (int r = 0; r < 4; ++r) {
        int i = 16 * w + g * 4 + r;
        bool rowok = (i < NTOK);
        float sv[7];
        float mx = -1e30f;
        #pragma unroll
        for (int j = 0; j < 7; ++j) {
            int col = 16 * j + li;
            float t = s[j][r];
            if (rowok && col < NTOK) t += bp[i * NTOK + col] + mp[i * NTOK + col];
            else t = -1e30f;
            sv[j] = t;
            mx = fmaxf(mx, t);
        }
        mx = fmaxf(mx, __shfl_xor(mx, 1));
        mx = fmaxf(mx, __shfl_xor(mx, 2));
        mx = fmaxf(mx, __shfl_xor(mx, 4));
        mx = fmaxf(mx, __shfl_xor(mx, 8));
        float sum = 0.f;
        #pragma unroll
        for (int j = 0; j < 7; ++j) {
            float p = __expf(sv[j] - mx);
            sum += p;
            Ps[w][g * 4 + r][16 * j + li] = (short)f2bf(p);
        }
        sum += __shfl_xor(sum, 1);
        sum += __shfl_xor(sum, 2);
        sum += __shfl_xor(sum, 4);
        sum += __shfl_xor(sum, 8);
        sinv[r] = 1.0f / sum;
    }

    __syncthreads();

    f32x4 o[2] = {};
    #pragma unroll
    for (int ks = 0; ks < 4; ++ks) {
        bf16x8 pa = *(bf16x8*)&Ps[w][li][ks * 32 + g * 8];
        #pragma unroll
        for (int ct = 0; ct < 2; ++ct) {
            bf16x8 vb = *(bf16x8*)&Vt[ct * 16 + li][ks * 32 + g * 8];
            o[ct] = __builtin_amdgcn_mfma_f32_16x16x32_bf16(pa, vb, o[ct], 0, 0, 0);
        }
    }

    #pragma unroll
    for (int ct = 0; ct < 2; ++ct) {
        #pragma unroll
        for (int r = 0; r < 4; ++r) {
            int i = 16 * w + g * 4 + r;
            if (i < NTOK) {
                int d = ct * 16 + li;
                qslot[i * 32 + d] = f2bf(o[ct][r] * sinv[r]);
            }
        }
    }
}

__global__ __launch_bounds__(256)
void k_proj_old(const unsigned short* __restrict__ qkvbuf, const float* __restrict__ w,
                const float* __restrict__ pb, float* __restrict__ out) {
    __shared__ short As[128][36];
    __shared__ short Bs[128][36];
    const int tid = threadIdx.x;
    const int m0 = blockIdx.x * 128, n0 = blockIdx.y * 128;
    const int wid = tid >> 6, l = tid & 63;
    const int wr = wid >> 1, wc = wid & 1;
    const int g = l >> 4, li = l & 15;
    const int srow = tid >> 1, scol = (tid & 1) * 16;

    unsigned row = m0 + srow;
    unsigned bw = row / 98u, nn_ = row - bw * 98u;
    const unsigned short* abase =
        qkvbuf + (size_t)bw * 48u * 3136u + (size_t)nn_ * 32u + scol;
    const float* bp = w + (size_t)(n0 + srow) * DIMC + scol;

    f32x4 acc[4][4] = {};

    for (int k0 = 0; k0 < DIMC; k0 += 32) {
        int hh = k0 >> 5;
        const unsigned short* ap = abase + (size_t)hh * 9408u;
        bf16x8 A0 = *(const bf16x8*)ap;
        bf16x8 A1 = *(const bf16x8*)(ap + 8);
        float4 b0 = *(const float4*)(bp + k0);
        float4 b1 = *(const float4*)(bp + k0 + 4);
        float4 b2 = *(const float4*)(bp + k0 + 8);
        float4 b3 = *(const float4*)(bp + k0 + 12);
        *(bf16x8*)&As[srow][scol]     = A0;
        *(bf16x8*)&As[srow][scol + 8] = A1;
        *(bf16x8*)&Bs[srow][scol]     = cvt8(b0, b1);
        *(bf16x8*)&Bs[srow][scol + 8] = cvt8(b2, b3);
        __syncthreads();
        bf16x8 af[4], bfr[4];
        #pragma unroll
        for (int mm = 0; mm < 4; ++mm)
            af[mm] = *(bf16x8*)&As[wr * 64 + mm * 16 + li][g * 8];
        #pragma unroll
        for (int nn = 0; nn < 4; ++nn)
            bfr[nn] = *(bf16x8*)&Bs[wc * 64 + nn * 16 + li][g * 8];
        #pragma unroll
        for (int mm = 0; mm < 4; ++mm)
            #pragma unroll
            for (int nn = 0; nn < 4; ++nn)
                acc[mm][nn] = __builtin_amdgcn_mfma_f32_16x16x32_bf16(
                    af[mm], bfr[nn], acc[mm][nn], 0, 0, 0);
        __syncthreads();
    }

    #pragma unroll
    for (int mm = 0; mm < 4; ++mm) {
        #pragma unroll
        for (int nn = 0; nn < 4; ++nn) {
            int col = n0 + wc * 64 + nn * 16 + li;
            float bv = pb[col];
            #pragma unroll
            for (int r = 0; r < 4; ++r) {
                int row2 = m0 + wr * 64 + mm * 16 + g * 4 + r;
                out[(size_t)row2 * DIMC + col] = acc[mm][nn][r] + bv;
            }
        }
    }
}

extern "C" void kernel_launch(void* const* d_in, const int* in_sizes, int n_in,
                              void* d_out, int out_size, void* d_ws, size_t ws_size,
                              hipStream_t stream) {
    const float* x          = (const float*)d_in[0];
    const float* mask       = (const float*)d_in[1];
    const float* qkv_w      = (const float*)d_in[2];
    const float* qkv_b      = (const float*)d_in[3];
    const float* proj_w     = (const float*)d_in[4];
    const float* proj_b     = (const float*)d_in[5];
    const float* bias_table = (const float*)d_in[6];
    const int*   rel_idx    = (const int*)d_in[7];
    float* out = (float*)d_out;

    const size_t QKV_BYTES = (size_t)16384 * 3 * 3136 * 2;   // 308,281,344
    const size_t XB_BYTES  = (size_t)100352 * 512 * 2;       // 102,760,448
    const size_t WQ_BYTES  = (size_t)1536 * 512 * 2;
    const size_t WP_BYTES  = (size_t)512 * 512 * 2;

    unsigned short* qkvbuf = (unsigned short*)d_ws;
    const size_t need = QKV_BYTES + XB_BYTES + WQ_BYTES + WP_BYTES;

    if (ws_size >= need) {
        unsigned short* xb  = (unsigned short*)((char*)d_ws + QKV_BYTES);
        unsigned short* wqb = xb + (size_t)100352 * 512;
        unsigned short* wpb = wqb + (size_t)1536 * 512;
        float* bm_t = (float*)xb;   // alias: xb dead after k_qkv3 (51.4MB < 102.8MB)

        k_cvt3<<<dim3(25600), dim3(256), 0, stream>>>(x, xb, qkv_w, wqb, proj_w, wpb);

        k_qkv3<<<dim3(2352), dim3(512), 0, stream>>>(xb, wqb, qkv_b, qkvbuf);
        k_bm2<<<dim3(1024), dim3(256), 0, stream>>>(bias_table, rel_idx, mask, bm_t);
        k_attn4<<<dim3(2048), dim3(448), 0, stream>>>(qkvbuf, bm_t);
        k_proj3<<<dim3(784), dim3(512), 0, stream>>>(qkvbuf, wpb, proj_b, out);
    } else {
        float* bias_full = (float*)((char*)d_ws + QKV_BYTES);
        k_bias<<<dim3(16, 98), dim3(128), 0, stream>>>(bias_table, rel_idx, bias_full);
        k_qkv_old<<<dim3(784, 12), dim3(256), 0, stream>>>(x, qkv_w, qkv_b, qkvbuf);
        k_attn_old<<<dim3(16384), dim3(448), 0, stream>>>(qkvbuf, mask, bias_full);
        k_proj_old<<<dim3(784, 4), dim3(256), 0, stream>>>(qkvbuf, proj_w, proj_b, out);
    }
}

// Round 17
// 540.961 us; speedup vs baseline: 1.0926x; 1.0083x over previous
//
#include <hip/hip_runtime.h>
#include <hip/hip_bf16.h>
#include <stdint.h>

#define DIMC 512
#define NTOK 98
// M_TOTAL = 1024*98 = 100352 = 392 * 256

typedef float f32x4 __attribute__((ext_vector_type(4)));
typedef short bf16x8 __attribute__((ext_vector_type(8)));
typedef short bf16x4 __attribute__((ext_vector_type(4)));

__device__ inline unsigned short f2bf(float f) {
    union { float f; uint32_t u; } v; v.f = f;
    uint32_t r = v.u + 0x7fffu + ((v.u >> 16) & 1u);
    return (unsigned short)(r >> 16);
}

__device__ inline bf16x8 cvt8(float4 a, float4 b) {
    bf16x8 r;
    r[0] = (short)f2bf(a.x); r[1] = (short)f2bf(a.y);
    r[2] = (short)f2bf(a.z); r[3] = (short)f2bf(a.w);
    r[4] = (short)f2bf(b.x); r[5] = (short)f2bf(b.y);
    r[6] = (short)f2bf(b.z); r[7] = (short)f2bf(b.w);
    return r;
}

__device__ __forceinline__ void gload16(const void* g, void* l) {
    __builtin_amdgcn_global_load_lds(
        (const __attribute__((address_space(1))) unsigned int*)g,
        (__attribute__((address_space(3))) unsigned int*)l, 16, 0, 0);
}

#define CFENCE() __asm__ __volatile__("" ::: "memory")
#define BARRIER() do { CFENCE(); __builtin_amdgcn_s_barrier(); CFENCE(); } while (0)

// ------- fused prep: fp32->bf16 cvt (x, qkv_w, proj_w) + bias/mask table -------
// bm segment (blocks 25600..26623) hides under the cvt segments' BW tail.
__global__ void k_prep(const float* __restrict__ s0, unsigned short* __restrict__ d0,
                       const float* __restrict__ s1, unsigned short* __restrict__ d1,
                       const float* __restrict__ s2, unsigned short* __restrict__ d2,
                       const float* __restrict__ table, const int* __restrict__ idx,
                       const float* __restrict__ mask, float* __restrict__ bm_t) {
    int b = blockIdx.x;
    if (b >= 25600) {
        int slice = b - 25600;             // 0..1023 = b64*16 + h
        int b64 = slice >> 4, h = slice & 15;
        float* dst = bm_t + (size_t)slice * 12544;   // 112*112, transposed layout
        const float* mp = mask + (size_t)b64 * 9604;
        for (int t = threadIdx.x; t < 12544; t += blockDim.x) {
            int i = t / 112, c = t - i * 112;
            float v = -1e9f;
            if (c < NTOK && i < NTOK)
                v = (table[idx[i * NTOK + c] * 16 + h] + mp[i * NTOK + c])
                    * 1.4426950408889634f;
            dst[t] = v;
        }
        return;
    }
    const float* src; unsigned short* dst; int i;
    if (b < 25088)      { src = s0; dst = d0; i = b * 256 + threadIdx.x; }
    else if (b < 25472) { src = s1; dst = d1; i = (b - 25088) * 256 + threadIdx.x; }
    else                { src = s2; dst = d2; i = (b - 25472) * 256 + threadIdx.x; }
    float4 a = *(const float4*)(src + (size_t)i * 8);
    float4 c = *(const float4*)(src + (size_t)i * 8 + 4);
    *(bf16x8*)(dst + (size_t)i * 8) = cvt8(a, c);
}

// ---------------- standalone cvt + bm (middle path: bm_t aliases xb) -----------
__global__ void k_cvt3(const float* __restrict__ s0, unsigned short* __restrict__ d0,
                       const float* __restrict__ s1, unsigned short* __restrict__ d1,
                       const float* __restrict__ s2, unsigned short* __restrict__ d2) {
    int b = blockIdx.x;
    const float* src; unsigned short* dst; int i;
    if (b < 25088)      { src = s0; dst = d0; i = b * 256 + threadIdx.x; }
    else if (b < 25472) { src = s1; dst = d1; i = (b - 25088) * 256 + threadIdx.x; }
    else                { src = s2; dst = d2; i = (b - 25472) * 256 + threadIdx.x; }
    float4 a = *(const float4*)(src + (size_t)i * 8);
    float4 c = *(const float4*)(src + (size_t)i * 8 + 4);
    *(bf16x8*)(dst + (size_t)i * 8) = cvt8(a, c);
}

__global__ void k_bm2(const float* __restrict__ table, const int* __restrict__ idx,
                      const float* __restrict__ mask, float* __restrict__ bm_t) {
    int slice = blockIdx.x;
    int b64 = slice >> 4, h = slice & 15;
    float* dst = bm_t + (size_t)slice * 12544;
    const float* mp = mask + (size_t)b64 * 9604;
    for (int t = threadIdx.x; t < 12544; t += blockDim.x) {
        int i = t / 112, c = t - i * 112;
        float v = -1e9f;
        if (c < NTOK && i < NTOK)
            v = (table[idx[i * NTOK + c] * 16 + h] + mp[i * NTOK + c])
                * 1.4426950408889634f;
        dst[t] = v;
    }
}

// ============ qkv GEMM: 256^2, BK=64, 8 waves, 8-phase, ONE barrier per phase ===
__global__ __launch_bounds__(512, 2)
void k_qkv3(const unsigned short* __restrict__ xb, const unsigned short* __restrict__ wb,
            const float* __restrict__ qb, unsigned short* __restrict__ qkvbuf) {
    __shared__ unsigned short As[2][2][128 * 64];   // [slot][half][row*64 + col]
    __shared__ unsigned short Bs[2][2][128 * 64];
    const int tid = threadIdx.x;
    const int wid = tid >> 6, l = tid & 63, g = l >> 4, li = l & 15;
    const int wm = wid >> 2, wn = wid & 3;
    const int id = blockIdx.x;                     // 2352 = 8 * 49 * 6
    const int xcd = id & 7, local = id >> 3;
    const int mt = xcd * 49 + local / 6;
    const int nt = local - (local / 6) * 6;
    const int m0 = mt * 256, n0 = nt * 256;

    const int srow = tid >> 3;
    const int scg  = tid & 7;
    const int sxor = (scg ^ (srow & 7)) * 8;       // elems
    const unsigned short* aG[2][2];
    const unsigned short* bG[2][2];
    #pragma unroll
    for (int h = 0; h < 2; ++h) {
        aG[h][0] = xb + (size_t)(m0 + h * 128 + srow) * DIMC + sxor;
        aG[h][1] = xb + (size_t)(m0 + h * 128 + 64 + srow) * DIMC + sxor;
        bG[h][0] = wb + (size_t)(n0 + h * 128 + srow) * DIMC + sxor;
        bG[h][1] = wb + (size_t)(n0 + h * 128 + 64 + srow) * DIMC + sxor;
    }
    const int lb0 = wid * 512;          // chunk-set 0 (rows 0-63 of a half)
    const int lb1 = 4096 + wid * 512;   // chunk-set 1 (rows 64-127)

    const int axor0 = ((0 + g) ^ (li & 7)) * 8;
    const int axor1 = ((4 + g) ^ (li & 7)) * 8;
    const int arow = li * 64;
    const int brow = (wn & 1) * 4096 + li * 64;
    const int bh = wn >> 1;

    f32x4 acc[8][4] = {};

    // prologue: tile 0, pairs in order b0, b1, a0, a1
    gload16(bG[0][0], &Bs[0][0][lb0]); gload16(bG[1][0], &Bs[0][1][lb0]);
    gload16(bG[0][1], &Bs[0][0][lb1]); gload16(bG[1][1], &Bs[0][1][lb1]);
    gload16(aG[0][0], &As[0][0][lb0]); gload16(aG[1][0], &As[0][1][lb0]);
    gload16(aG[0][1], &As[0][0][lb1]); gload16(aG[1][1], &As[0][1][lb1]);

    #pragma unroll
    for (int kt = 0; kt < 8; ++kt) {
        const int s = kt & 1, p = s ^ 1;
        const int ko = (kt + 1) * 64;
        bf16x8 bfr[4][2];
        #pragma unroll
        for (int q = 0; q < 4; ++q) {
            const int mq0 = 2 * q;
            bf16x8 a00, a01, a10, a11;
            if (q == 1 || q == 3) {  // pre-barrier: retired by earlier own-wave wait
                a00 = *(const bf16x8*)&As[s][wm][arow + mq0 * 1024 + axor0];
                a01 = *(const bf16x8*)&As[s][wm][arow + mq0 * 1024 + axor1];
                a10 = *(const bf16x8*)&As[s][wm][arow + (mq0 + 1) * 1024 + axor0];
                a11 = *(const bf16x8*)&As[s][wm][arow + (mq0 + 1) * 1024 + axor1];
            }
            if (kt < 7) {
                if (q == 0) { gload16(bG[0][0] + ko, &Bs[p][0][lb0]);
                              gload16(bG[1][0] + ko, &Bs[p][1][lb0]); }
                if (q == 1) { gload16(bG[0][1] + ko, &Bs[p][0][lb1]);
                              gload16(bG[1][1] + ko, &Bs[p][1][lb1]); }
                if (q == 2) { gload16(aG[0][0] + ko, &As[p][0][lb0]);
                              gload16(aG[1][0] + ko, &As[p][1][lb0]); }
                if (q == 3) { gload16(aG[0][1] + ko, &As[p][0][lb1]);
                              gload16(aG[1][1] + ko, &As[p][1][lb1]); }
            }
            if (q == 0) {
                if (kt < 7) __asm__ __volatile__("s_waitcnt vmcnt(4)" ::: "memory");
                else        __asm__ __volatile__("s_waitcnt vmcnt(2)" ::: "memory");
            } else if (q == 2) {
                if (kt < 7) __asm__ __volatile__("s_waitcnt vmcnt(6)" ::: "memory");
                else        __asm__ __volatile__("s_waitcnt vmcnt(0)" ::: "memory");
            } else {
                if (kt < 7) __asm__ __volatile__("s_waitcnt vmcnt(6)" ::: "memory");
            }
            BARRIER();   // single barrier per phase
            if (q == 0) {
                #pragma unroll
                for (int nq = 0; nq < 4; ++nq) {
                    bfr[nq][0] = *(const bf16x8*)&Bs[s][bh][brow + nq * 1024 + axor0];
                    bfr[nq][1] = *(const bf16x8*)&Bs[s][bh][brow + nq * 1024 + axor1];
                }
            }
            if (q == 0 || q == 2) {  // post-barrier: retired by THIS phase's wait
                a00 = *(const bf16x8*)&As[s][wm][arow + mq0 * 1024 + axor0];
                a01 = *(const bf16x8*)&As[s][wm][arow + mq0 * 1024 + axor1];
                a10 = *(const bf16x8*)&As[s][wm][arow + (mq0 + 1) * 1024 + axor0];
                a11 = *(const bf16x8*)&As[s][wm][arow + (mq0 + 1) * 1024 + axor1];
            }
            __asm__ __volatile__("s_waitcnt lgkmcnt(0)" ::: "memory");
            __builtin_amdgcn_s_setprio(1);
            #pragma unroll
            for (int nq = 0; nq < 4; ++nq) {
                acc[mq0][nq] = __builtin_amdgcn_mfma_f32_16x16x32_bf16(
                    bfr[nq][0], a00, acc[mq0][nq], 0, 0, 0);
                acc[mq0][nq] = __builtin_amdgcn_mfma_f32_16x16x32_bf16(
                    bfr[nq][1], a01, acc[mq0][nq], 0, 0, 0);
                acc[mq0 + 1][nq] = __builtin_amdgcn_mfma_f32_16x16x32_bf16(
                    bfr[nq][0], a10, acc[mq0 + 1][nq], 0, 0, 0);
                acc[mq0 + 1][nq] = __builtin_amdgcn_mfma_f32_16x16x32_bf16(
                    bfr[nq][1], a11, acc[mq0 + 1][nq], 0, 0, 0);
            }
            __builtin_amdgcn_s_setprio(0);
        }
    }

    // epilogue: swapped layout -> thread's quad = row (m=li) x 4 consecutive cols
    #pragma unroll
    for (int mq = 0; mq < 8; ++mq) {
        int row = m0 + wm * 128 + mq * 16 + li;
        unsigned bw = (unsigned)row / 98u;
        unsigned nn_ = (unsigned)row - bw * 98u;
        unsigned short* rbase = qkvbuf + (size_t)bw * 150528u + nn_ * 32u;
        #pragma unroll
        for (int nq = 0; nq < 4; ++nq) {
            int col0 = n0 + wn * 64 + nq * 16 + g * 4;
            int which = col0 >> 9;
            int h = (col0 >> 5) & 15;
            int d0 = col0 & 31;
            float4 bv = *(const float4*)(qb + col0);
            float sc = (which == 0)
                ? (0.17677669529663689f * 1.4426950408889634f) : 1.0f;
            bf16x4 pk;
            pk[0] = (short)f2bf((acc[mq][nq][0] + bv.x) * sc);
            pk[1] = (short)f2bf((acc[mq][nq][1] + bv.y) * sc);
            pk[2] = (short)f2bf((acc[mq][nq][2] + bv.z) * sc);
            pk[3] = (short)f2bf((acc[mq][nq][3] + bv.w) * sc);
            *(bf16x4*)(rbase + (size_t)(h * 3 + which) * 3136u + d0) = pk;
        }
    }
}

// ============ proj GEMM: same 8-phase single-barrier pipeline, A gathered ======
__global__ __launch_bounds__(512, 2)
void k_proj3(const unsigned short* __restrict__ qkvbuf,
             const unsigned short* __restrict__ wb,
             const float* __restrict__ pb, float* __restrict__ out) {
    __shared__ unsigned short As[2][2][128 * 64];
    __shared__ unsigned short Bs[2][2][128 * 64];
    const int tid = threadIdx.x;
    const int wid = tid >> 6, l = tid & 63, g = l >> 4, li = l & 15;
    const int wm = wid >> 2, wn = wid & 3;
    const int id = blockIdx.x;                     // 784 = 8 * 49 * 2
    const int xcd = id & 7, local = id >> 3;
    const int mt = xcd * 49 + local / 2;
    const int nt = local & 1;
    const int m0 = mt * 256, n0 = nt * 256;

    const int srow = tid >> 3;
    const int scg  = tid & 7;
    const int cgx  = scg ^ (srow & 7);
    const unsigned short* aG[2][2];
    const unsigned short* bG[2][2];
    #pragma unroll
    for (int h = 0; h < 2; ++h) {
        #pragma unroll
        for (int i = 0; i < 2; ++i) {
            int R = m0 + h * 128 + i * 64 + srow;
            unsigned bw = (unsigned)R / 98u, nn = (unsigned)R - bw * 98u;
            aG[h][i] = qkvbuf + (size_t)bw * 150528u + nn * 32u
                       + (size_t)(cgx >> 2) * 9408u + (cgx & 3) * 8;
            bG[h][i] = wb + (size_t)(n0 + h * 128 + i * 64 + srow) * DIMC + cgx * 8;
        }
    }
    const int lb0 = wid * 512;
    const int lb1 = 4096 + wid * 512;

    const int axor0 = ((0 + g) ^ (li & 7)) * 8;
    const int axor1 = ((4 + g) ^ (li & 7)) * 8;
    const int arow = li * 64;
    const int brow = (wn & 1) * 4096 + li * 64;
    const int bh = wn >> 1;

    f32x4 acc[8][4] = {};

    gload16(bG[0][0], &Bs[0][0][lb0]); gload16(bG[1][0], &Bs[0][1][lb0]);
    gload16(bG[0][1], &Bs[0][0][lb1]); gload16(bG[1][1], &Bs[0][1][lb1]);
    gload16(aG[0][0], &As[0][0][lb0]); gload16(aG[1][0], &As[0][1][lb0]);
    gload16(aG[0][1], &As[0][0][lb1]); gload16(aG[1][1], &As[0][1][lb1]);

    #pragma unroll
    for (int kt = 0; kt < 8; ++kt) {
        const int s = kt & 1, p = s ^ 1;
        const size_t ao = (size_t)(kt + 1) * 18816u;
        const int ko = (kt + 1) * 64;
        bf16x8 bfr[4][2];
        #pragma unroll
        for (int q = 0; q < 4; ++q) {
            const int mq0 = 2 * q;
            bf16x8 a00, a01, a10, a11;
            if (q == 1 || q == 3) {
                a00 = *(const bf16x8*)&As[s][wm][arow + mq0 * 1024 + axor0];
                a01 = *(const bf16x8*)&As[s][wm][arow + mq0 * 1024 + axor1];
                a10 = *(const bf16x8*)&As[s][wm][arow + (mq0 + 1) * 1024 + axor0];
                a11 = *(const bf16x8*)&As[s][wm][arow + (mq0 + 1) * 1024 + axor1];
            }
            if (kt < 7) {
                if (q == 0) { gload16(bG[0][0] + ko, &Bs[p][0][lb0]);
                              gload16(bG[1][0] + ko, &Bs[p][1][lb0]); }
                if (q == 1) { gload16(bG[0][1] + ko, &Bs[p][0][lb1]);
                              gload16(bG[1][1] + ko, &Bs[p][1][lb1]); }
                if (q == 2) { gload16(aG[0][0] + ao, &As[p][0][lb0]);
                              gload16(aG[1][0] + ao, &As[p][1][lb0]); }
                if (q == 3) { gload16(aG[0][1] + ao, &As[p][0][lb1]);
                              gload16(aG[1][1] + ao, &As[p][1][lb1]); }
            }
            if (q == 0) {
                if (kt < 7) __asm__ __volatile__("s_waitcnt vmcnt(4)" ::: "memory");
                else        __asm__ __volatile__("s_waitcnt vmcnt(2)" ::: "memory");
            } else if (q == 2) {
                if (kt < 7) __asm__ __volatile__("s_waitcnt vmcnt(6)" ::: "memory");
                else        __asm__ __volatile__("s_waitcnt vmcnt(0)" ::: "memory");
            } else {
                if (kt < 7) __asm__ __volatile__("s_waitcnt vmcnt(6)" ::: "memory");
            }
            BARRIER();
            if (q == 0) {
                #pragma unroll
                for (int nq = 0; nq < 4; ++nq) {
                    bfr[nq][0] = *(const bf16x8*)&Bs[s][bh][brow + nq * 1024 + axor0];
                    bfr[nq][1] = *(const bf16x8*)&Bs[s][bh][brow + nq * 1024 + axor1];
                }
            }
            if (q == 0 || q == 2) {
                a00 = *(const bf16x8*)&As[s][wm][arow + mq0 * 1024 + axor0];
                a01 = *(const bf16x8*)&As[s][wm][arow + mq0 * 1024 + axor1];
                a10 = *(const bf16x8*)&As[s][wm][arow + (mq0 + 1) * 1024 + axor0];
                a11 = *(const bf16x8*)&As[s][wm][arow + (mq0 + 1) * 1024 + axor1];
            }
            __asm__ __volatile__("s_waitcnt lgkmcnt(0)" ::: "memory");
            __builtin_amdgcn_s_setprio(1);
            #pragma unroll
            for (int nq = 0; nq < 4; ++nq) {
                acc[mq0][nq] = __builtin_amdgcn_mfma_f32_16x16x32_bf16(
                    bfr[nq][0], a00, acc[mq0][nq], 0, 0, 0);
                acc[mq0][nq] = __builtin_amdgcn_mfma_f32_16x16x32_bf16(
                    bfr[nq][1], a01, acc[mq0][nq], 0, 0, 0);
                acc[mq0 + 1][nq] = __builtin_amdgcn_mfma_f32_16x16x32_bf16(
                    bfr[nq][0], a10, acc[mq0 + 1][nq], 0, 0, 0);
                acc[mq0 + 1][nq] = __builtin_amdgcn_mfma_f32_16x16x32_bf16(
                    bfr[nq][1], a11, acc[mq0 + 1][nq], 0, 0, 0);
            }
            __builtin_amdgcn_s_setprio(0);
        }
    }

    #pragma unroll
    for (int mq = 0; mq < 8; ++mq) {
        int row2 = m0 + wm * 128 + mq * 16 + li;
        float* orow = out + (size_t)row2 * DIMC;
        #pragma unroll
        for (int nq = 0; nq < 4; ++nq) {
            int col0 = n0 + wn * 64 + nq * 16 + g * 4;
            float4 bv = *(const float4*)(pb + col0);
            float4 v;
            v.x = acc[mq][nq][0] + bv.x;
            v.y = acc[mq][nq][1] + bv.y;
            v.z = acc[mq][nq][2] + bv.z;
            v.w = acc[mq][nq][3] + bv.w;
            *(float4*)(orow + col0) = v;
        }
    }
}

// ------- attention: persistent, dbuf K/V, SWAPPED QK^T (S^T = K x Q) -----------
__global__ __launch_bounds__(448)
void k_attn4(unsigned short* __restrict__ qkvbuf, const float* __restrict__ bm_t) {
    __shared__ short Ks[2][112][36];
    __shared__ short Vt[2][32][132];
    __shared__ short Ps[7][16][132];   // [wave][q-row][k]; k 112..127 zeroed once

    const int tid = threadIdx.x;
    const int w = tid >> 6, l = tid & 63, g = l >> 4, li = l & 15;

    const int id = blockIdx.x;                 // 2048
    const int slice = id >> 1, mh = id & 1;    // slice = (b%64)*16 + h

    const float* bmp = bm_t + (size_t)slice * 12544 + (16 * w + li) * 112 + g * 4;
    f32x4 bmf[7];
    #pragma unroll
    for (int j = 0; j < 7; ++j)
        bmf[j] = *(const f32x4*)(bmp + 16 * j);

    #pragma unroll
    for (int bsel = 0; bsel < 2; ++bsel) {
        Ks[bsel][98 + (tid >> 5)][tid & 31] = 0;
        for (int t2 = tid; t2 < 32 * 34; t2 += 448) {
            int d = t2 / 34, c = t2 % 34;
            Vt[bsel][d][98 + c] = 0;
        }
    }
    {
        bf16x4 z = {};
        *(bf16x4*)&Ps[w][li][112 + g * 4] = z;
    }

    const int krow = tid >> 2, kseg = (tid & 3) * 8;
    const size_t step = (size_t)1024 * 9408;
    unsigned short* qslot = qkvbuf + (size_t)(mh * 8192 + slice) * 9408;

    bf16x8 kreg = {}, vreg = {}, aqc, aqn;
    if (tid < 392) {
        kreg = *(const bf16x8*)(qslot + 3136 + krow * 32 + kseg);
        vreg = *(const bf16x8*)(qslot + 6272 + krow * 32 + kseg);
    }
    aqc = *(const bf16x8*)(qslot + (16 * w + li) * 32 + g * 8);
    if (tid < 392) {
        *(bf16x8*)&Ks[0][krow][kseg] = kreg;
        #pragma unroll
        for (int j = 0; j < 8; ++j) Vt[0][kseg + j][krow] = vreg[j];
    }

    for (int it = 0; it < 8; ++it) {
        const int b = it & 1;
        __syncthreads();   // buf b staged visible

        unsigned short* qnext = qslot + step;
        if (it < 7) {
            if (tid < 392) {
                kreg = *(const bf16x8*)(qnext + 3136 + krow * 32 + kseg);
                vreg = *(const bf16x8*)(qnext + 6272 + krow * 32 + kseg);
            }
            aqn = *(const bf16x8*)(qnext + (16 * w + li) * 32 + g * 8);
        }

        // S^T = K @ Q^T + bias^T: lane holds S[q=li][k=16j+g*4+r]
        f32x4 s[7];
        __builtin_amdgcn_s_setprio(1);
        #pragma unroll
        for (int j = 0; j < 7; ++j) {
            bf16x8 bk = *(bf16x8*)&Ks[b][16 * j + li][g * 8];
            s[j] = __builtin_amdgcn_mfma_f32_16x16x32_bf16(bk, aqc, bmf[j], 0, 0, 0);
        }
        __builtin_amdgcn_s_setprio(0);

        float p[7][4];
        float sum = 0.f;
        #pragma unroll
        for (int j = 0; j < 7; ++j)
            #pragma unroll
            for (int r = 0; r < 4; ++r) {
                p[j][r] = exp2f(s[j][r]);
                sum += p[j][r];
            }
        sum += __shfl_xor(sum, 16);
        sum += __shfl_xor(sum, 32);
        float sinv = 1.0f / sum;

        #pragma unroll
        for (int j = 0; j < 7; ++j) {
            bf16x4 pk;
            pk[0] = (short)f2bf(p[j][0] * sinv);
            pk[1] = (short)f2bf(p[j][1] * sinv);
            pk[2] = (short)f2bf(p[j][2] * sinv);
            pk[3] = (short)f2bf(p[j][3] * sinv);
            *(bf16x4*)&Ps[w][li][16 * j + g * 4] = pk;
        }

        __asm__ __volatile__("s_waitcnt lgkmcnt(0)" ::: "memory");
        __builtin_amdgcn_sched_barrier(0);

        f32x4 o[2] = {};
        __builtin_amdgcn_s_setprio(1);
        #pragma unroll
        for (int ks = 0; ks < 4; ++ks) {
            bf16x8 pa = *(bf16x8*)&Ps[w][li][ks * 32 + g * 8];
            #pragma unroll
            for (int ct = 0; ct < 2; ++ct) {
                bf16x8 vb = *(bf16x8*)&Vt[b][ct * 16 + li][ks * 32 + g * 8];
                o[ct] = __builtin_amdgcn_mfma_f32_16x16x32_bf16(pa, vb, o[ct], 0, 0, 0);
            }
        }
        __builtin_amdgcn_s_setprio(0);

        #pragma unroll
        for (int ct = 0; ct < 2; ++ct) {
            #pragma unroll
            for (int r = 0; r < 4; ++r) {
                int i = 16 * w + g * 4 + r;
                if (i < NTOK) {
                    int d = ct * 16 + li;
                    qslot[i * 32 + d] = f2bf(o[ct][r]);   // P pre-normalized
                }
            }
        }

        if (it < 7) {
            if (tid < 392) {
                *(bf16x8*)&Ks[b ^ 1][krow][kseg] = kreg;
                #pragma unroll
                for (int j = 0; j < 8; ++j) Vt[b ^ 1][kseg + j][krow] = vreg[j];
            }
            aqc = aqn;
            qslot = qnext;
        }
    }
}

// ================= fallback (round-1) path =====================================
__global__ void k_bias(const float* __restrict__ table, const int* __restrict__ idx,
                       float* __restrict__ bias_full) {
    int h = blockIdx.x, i = blockIdx.y, j = threadIdx.x;
    if (j < NTOK)
        bias_full[(h * NTOK + i) * NTOK + j] = table[idx[i * NTOK + j] * 16 + h];
}

__global__ __launch_bounds__(256)
void k_qkv_old(const float* __restrict__ x, const float* __restrict__ w,
               const float* __restrict__ qb, unsigned short* __restrict__ qkvbuf) {
    __shared__ short As[128][36];
    __shared__ short Bs[128][36];
    const int tid = threadIdx.x;
    const int m0 = blockIdx.x * 128, n0 = blockIdx.y * 128;
    const int wid = tid >> 6, l = tid & 63;
    const int wr = wid >> 1, wc = wid & 1;
    const int g = l >> 4, li = l & 15;
    const int srow = tid >> 1, scol = (tid & 1) * 16;

    f32x4 acc[4][4] = {};
    const float* ap = x + (size_t)(m0 + srow) * DIMC + scol;
    const float* bp = w + (size_t)(n0 + srow) * DIMC + scol;

    for (int k0 = 0; k0 < DIMC; k0 += 32) {
        float4 a0 = *(const float4*)(ap + k0);
        float4 a1 = *(const float4*)(ap + k0 + 4);
        float4 a2 = *(const float4*)(ap + k0 + 8);
        float4 a3 = *(const float4*)(ap + k0 + 12);
        float4 b0 = *(const float4*)(bp + k0);
        float4 b1 = *(const float4*)(bp + k0 + 4);
        float4 b2 = *(const float4*)(bp + k0 + 8);
        float4 b3 = *(const float4*)(bp + k0 + 12);
        *(bf16x8*)&As[srow][scol]     = cvt8(a0, a1);
        *(bf16x8*)&As[srow][scol + 8] = cvt8(a2, a3);
        *(bf16x8*)&Bs[srow][scol]     = cvt8(b0, b1);
        *(bf16x8*)&Bs[srow][scol + 8] = cvt8(b2, b3);
        __syncthreads();
        bf16x8 af[4], bfr[4];
        #pragma unroll
        for (int mm = 0; mm < 4; ++mm)
            af[mm] = *(bf16x8*)&As[wr * 64 + mm * 16 + li][g * 8];
        #pragma unroll
        for (int nn = 0; nn < 4; ++nn)
            bfr[nn] = *(bf16x8*)&Bs[wc * 64 + nn * 16 + li][g * 8];
        #pragma unroll
        for (int mm = 0; mm < 4; ++mm)
            #pragma unroll
            for (int nn = 0; nn < 4; ++nn)
                acc[mm][nn] = __builtin_amdgcn_mfma_f32_16x16x32_bf16(
                    af[mm], bfr[nn], acc[mm][nn], 0, 0, 0);
        __syncthreads();
    }

    #pragma unroll
    for (int mm = 0; mm < 4; ++mm) {
        #pragma unroll
        for (int nn = 0; nn < 4; ++nn) {
            int col = n0 + wc * 64 + nn * 16 + li;
            int which = col >> 9;
            int h = (col >> 5) & 15;
            int d = col & 31;
            float bv = qb[col];
            #pragma unroll
            for (int r = 0; r < 4; ++r) {
                int row = m0 + wr * 64 + mm * 16 + g * 4 + r;
                unsigned bw = (unsigned)row / 98u;
                unsigned nn_ = (unsigned)row - bw * 98u;
                float v = acc[mm][nn][r] + bv;
                if (which == 0) v *= 0.17677669529663689f;
                qkvbuf[(size_t)((bw * 16u + h) * 3u + which) * 3136u + nn_ * 32u + d] =
                    f2bf(v);
            }
        }
    }
}

__global__ __launch_bounds__(448)
void k_attn_old(unsigned short* __restrict__ qkvbuf, const float* __restrict__ mask,
                const float* __restrict__ bias_full) {
    __shared__ short Ks[112][36];
    __shared__ short Vt[32][132];
    __shared__ short Ps[7][16][132];

    const int tid = threadIdx.x;
    const int w = tid >> 6, l = tid & 63, g = l >> 4, li = l & 15;
    const int bh = blockIdx.x;
    const int b = bh >> 4, h = bh & 15;

    unsigned short* qslot = qkvbuf + (size_t)bh * 3 * 3136;
    const unsigned short* kslot = qslot + 3136;
    const unsigned short* vslot = qslot + 6272;

    if (tid < 392) {
        int row = tid >> 2, seg = (tid & 3) * 8;
        bf16x8 kv = *(const bf16x8*)(kslot + row * 32 + seg);
        *(bf16x8*)&Ks[row][seg] = kv;
        bf16x8 vv = *(const bf16x8*)(vslot + row * 32 + seg);
        #pragma unroll
        for (int j = 0; j < 8; ++j) Vt[seg + j][row] = vv[j];
    }
    Ks[98 + (tid >> 5)][tid & 31] = 0;
    for (int t2 = tid; t2 < 32 * 34; t2 += 448) {
        int d = t2 / 34, c = t2 % 34;
        Vt[d][98 + c] = 0;
    }
    for (int t2 = l; t2 < 16 * 20; t2 += 64) {
        int r = t2 / 20, c = t2 % 20;
        Ps[w][r][112 + c] = 0;
    }

    bf16x8 aq = *(const bf16x8*)(qslot + (16 * w + li) * 32 + g * 8);

    __syncthreads();

    f32x4 s[7];
    #pragma unroll
    for (int j = 0; j < 7; ++j) {
        bf16x8 bk = *(bf16x8*)&Ks[16 * j + li][g * 8];
        f32x4 z = {};
        s[j] = __builtin_amdgcn_mfma_f32_16x16x32_bf16(aq, bk, z, 0, 0, 0);
    }

    const float* bp = bias_full + h * 9604;
    const float* mp = mask + (b & 63) * 9604;
    float sinv[4];
    #pragma unroll
    for (int r = 0; r < 4; ++r) {
        int i = 16 * w + g * 4 + r;
        bool rowok = (i < NTOK);
        float sv[7];
        float mx = -1e30f;
        #pragma unroll
        for (int j = 0; j < 7; ++j) {
            int col = 16 * j + li;
            float t = s[j][r];
            if (rowok && col < NTOK) t += bp[i * NTOK + col] + mp[i * NTOK + col];
            else t = -1e30f;
            sv[j] = t;
            mx = fmaxf(mx, t);
        }
        mx = fmaxf(mx, __shfl_xor(mx, 1));
        mx = fmaxf(mx, __shfl_xor(mx, 2));
        mx = fmaxf(mx, __shfl_xor(mx, 4));
        mx = fmaxf(mx, __shfl_xor(mx, 8));
        float sum = 0.f;
        #pragma unroll
        for (int j = 0; j < 7; ++j) {
            float p = __expf(sv[j] - mx);
            sum += p;
            Ps[w][g * 4 + r][16 * j + li] = (short)f2bf(p);
        }
        sum += __shfl_xor(sum, 1);
        sum += __shfl_xor(sum, 2);
        sum += __shfl_xor(sum, 4);
        sum += __shfl_xor(sum, 8);
        sinv[r] = 1.0f / sum;
    }

    __syncthreads();

    f32x4 o[2] = {};
    #pragma unroll
    for (int ks = 0; ks < 4; ++ks) {
        bf16x8 pa = *(bf16x8*)&Ps[w][li][ks * 32 + g * 8];
        #pragma unroll
        for (int ct = 0; ct < 2; ++ct) {
            bf16x8 vb = *(bf16x8*)&Vt[ct * 16 + li][ks * 32 + g * 8];
            o[ct] = __builtin_amdgcn_mfma_f32_16x16x32_bf16(pa, vb, o[ct], 0, 0, 0);
        }
    }

    #pragma unroll
    for (int ct = 0; ct < 2; ++ct) {
        #pragma unroll
        for (int r = 0; r < 4; ++r) {
            int i = 16 * w + g * 4 + r;
            if (i < NTOK) {
                int d = ct * 16 + li;
                qslot[i * 32 + d] = f2bf(o[ct][r] * sinv[r]);
            }
        }
    }
}

__global__ __launch_bounds__(256)
void k_proj_old(const unsigned short* __restrict__ qkvbuf, const float* __restrict__ w,
                const float* __restrict__ pb, float* __restrict__ out) {
    __shared__ short As[128][36];
    __shared__ short Bs[128][36];
    const int tid = threadIdx.x;
    const int m0 = blockIdx.x * 128, n0 = blockIdx.y * 128;
    const int wid = tid >> 6, l = tid & 63;
    const int wr = wid >> 1, wc = wid & 1;
    const int g = l >> 4, li = l & 15;
    const int srow = tid >> 1, scol = (tid & 1) * 16;

    unsigned row = m0 + srow;
    unsigned bw = row / 98u, nn_ = row - bw * 98u;
    const unsigned short* abase =
        qkvbuf + (size_t)bw * 48u * 3136u + (size_t)nn_ * 32u + scol;
    const float* bp = w + (size_t)(n0 + srow) * DIMC + scol;

    f32x4 acc[4][4] = {};

    for (int k0 = 0; k0 < DIMC; k0 += 32) {
        int hh = k0 >> 5;
        const unsigned short* ap = abase + (size_t)hh * 9408u;
        bf16x8 A0 = *(const bf16x8*)ap;
        bf16x8 A1 = *(const bf16x8*)(ap + 8);
        float4 b0 = *(const float4*)(bp + k0);
        float4 b1 = *(const float4*)(bp + k0 + 4);
        float4 b2 = *(const float4*)(bp + k0 + 8);
        float4 b3 = *(const float4*)(bp + k0 + 12);
        *(bf16x8*)&As[srow][scol]     = A0;
        *(bf16x8*)&As[srow][scol + 8] = A1;
        *(bf16x8*)&Bs[srow][scol]     = cvt8(b0, b1);
        *(bf16x8*)&Bs[srow][scol + 8] = cvt8(b2, b3);
        __syncthreads();
        bf16x8 af[4], bfr[4];
        #pragma unroll
        for (int mm = 0; mm < 4; ++mm)
            af[mm] = *(bf16x8*)&As[wr * 64 + mm * 16 + li][g * 8];
        #pragma unroll
        for (int nn = 0; nn < 4; ++nn)
            bfr[nn] = *(bf16x8*)&Bs[wc * 64 + nn * 16 + li][g * 8];
        #pragma unroll
        for (int mm = 0; mm < 4; ++mm)
            #pragma unroll
            for (int nn = 0; nn < 4; ++nn)
                acc[mm][nn] = __builtin_amdgcn_mfma_f32_16x16x32_bf16(
                    af[mm], bfr[nn], acc[mm][nn], 0, 0, 0);
        __syncthreads();
    }

    #pragma unroll
    for (int mm = 0; mm < 4; ++mm) {
        #pragma unroll
        for (int nn = 0; nn < 4; ++nn) {
            int col = n0 + wc * 64 + nn * 16 + li;
            float bv = pb[col];
            #pragma unroll
            for (int r = 0; r < 4; ++r) {
                int row2 = m0 + wr * 64 + mm * 16 + g * 4 + r;
                out[(size_t)row2 * DIMC + col] = acc[mm][nn][r] + bv;
            }
        }
    }
}

extern "C" void kernel_launch(void* const* d_in, const int* in_sizes, int n_in,
                              void* d_out, int out_size, void* d_ws, size_t ws_size,
                              hipStream_t stream) {
    const float* x          = (const float*)d_in[0];
    const float* mask       = (const float*)d_in[1];
    const float* qkv_w      = (const float*)d_in[2];
    const float* qkv_b      = (const float*)d_in[3];
    const float* proj_w     = (const float*)d_in[4];
    const float* proj_b     = (const float*)d_in[5];
    const float* bias_table = (const float*)d_in[6];
    const int*   rel_idx    = (const int*)d_in[7];
    float* out = (float*)d_out;

    const size_t QKV_BYTES = (size_t)16384 * 3 * 3136 * 2;   // 308,281,344
    const size_t XB_BYTES  = (size_t)100352 * 512 * 2;       // 102,760,448
    const size_t WQ_BYTES  = (size_t)1536 * 512 * 2;
    const size_t WP_BYTES  = (size_t)512 * 512 * 2;
    const size_t BM_BYTES  = (size_t)1024 * 12544 * 4;       //  51,380,224

    unsigned short* qkvbuf = (unsigned short*)d_ws;
    const size_t need  = QKV_BYTES + XB_BYTES + WQ_BYTES + WP_BYTES;
    const size_t need2 = need + BM_BYTES;

    if (ws_size >= need) {
        unsigned short* xb  = (unsigned short*)((char*)d_ws + QKV_BYTES);
        unsigned short* wqb = xb + (size_t)100352 * 512;
        unsigned short* wpb = wqb + (size_t)1536 * 512;

        if (ws_size >= need2) {
            // bm_t in its own region: bm work merges into the prep kernel
            // (overlaps cvt's BW tail; one fewer dispatch; no xb-alias hazard)
            float* bm_t = (float*)((char*)d_ws + need);
            k_prep<<<dim3(26624), dim3(256), 0, stream>>>(
                x, xb, qkv_w, wqb, proj_w, wpb, bias_table, rel_idx, mask, bm_t);
            k_qkv3<<<dim3(2352), dim3(512), 0, stream>>>(xb, wqb, qkv_b, qkvbuf);
            k_attn4<<<dim3(2048), dim3(448), 0, stream>>>(qkvbuf, bm_t);
            k_proj3<<<dim3(784), dim3(512), 0, stream>>>(qkvbuf, wpb, proj_b, out);
        } else {
            // bm_t aliases xb (dead after k_qkv3): bm2 must run after qkv3
            float* bm_t = (float*)xb;
            k_cvt3<<<dim3(25600), dim3(256), 0, stream>>>(x, xb, qkv_w, wqb,
                                                          proj_w, wpb);
            k_qkv3<<<dim3(2352), dim3(512), 0, stream>>>(xb, wqb, qkv_b, qkvbuf);
            k_bm2<<<dim3(1024), dim3(256), 0, stream>>>(bias_table, rel_idx, mask,
                                                        bm_t);
            k_attn4<<<dim3(2048), dim3(448), 0, stream>>>(qkvbuf, bm_t);
            k_proj3<<<dim3(784), dim3(512), 0, stream>>>(qkvbuf, wpb, proj_b, out);
        }
    } else {
        float* bias_full = (float*)((char*)d_ws + QKV_BYTES);
        k_bias<<<dim3(16, 98), dim3(128), 0, stream>>>(bias_table, rel_idx, bias_full);
        k_qkv_old<<<dim3(784, 12), dim3(256), 0, stream>>>(x, qkv_w, qkv_b, qkvbuf);
        k_attn_old<<<dim3(16384), dim3(448), 0, stream>>>(qkvbuf, mask, bias_full);
        k_proj_old<<<dim3(784, 4), dim3(256), 0, stream>>>(qkvbuf, proj_w, proj_b, out);
    }
}